// Round 2
// baseline (184.912 us; speedup 1.0000x reference)
//
#include <hip/hip_runtime.h>
#include <hip/hip_bf16.h>
#include <math.h>

#define IN_DIM 256
#define HD     512   // NUM_HEADS * OUT_DIM
#define NHEADS 8
#define DH     64
#define NSEQ   1024
#define BATCH  8

#define QSCALE 0.18033688011112042f   // 0.125 * log2(e): S in log2 domain

typedef unsigned short u16;
typedef unsigned int   u32;
typedef short bf16x8 __attribute__((ext_vector_type(8)));
typedef float f32x4  __attribute__((ext_vector_type(4)));
typedef float f32x16 __attribute__((ext_vector_type(16)));
typedef unsigned int u32x2 __attribute__((ext_vector_type(2)));

#if __has_builtin(__builtin_amdgcn_exp2f)
#define EXP2(x) __builtin_amdgcn_exp2f(x)
#else
#define EXP2(x) __expf(0.69314718056f * (x))
#endif

static __device__ __forceinline__ u16 f2bf(float x) {
    u32 u = __builtin_bit_cast(u32, x);
    u += 0x7FFFu + ((u >> 16) & 1u);     // RNE
    return (u16)(u >> 16);
}
static __device__ __forceinline__ u32 pk(u16 a, u16 b) {
    return (u32)a | ((u32)b << 16);
}
static __device__ __forceinline__ u32 cvtpk(float a, float b) {
    __hip_bfloat162 t = __float22bfloat162_rn(make_float2(a, b));
    u32 r; __builtin_memcpy(&r, &t, 4);
    return r;
}
// 16 bf16 (two uint4) -> f32x16 C-init
static __device__ __forceinline__ f32x16 maskinit(uint4 a, uint4 b) {
    f32x16 c;
    u32 ws[8] = {a.x, a.y, a.z, a.w, b.x, b.y, b.z, b.w};
#pragma unroll
    for (int i = 0; i < 8; ++i) {
        c[2 * i]     = __builtin_bit_cast(float, ws[i] << 16);
        c[2 * i + 1] = __builtin_bit_cast(float, ws[i] & 0xFFFF0000u);
    }
    return c;
}

// permlane32_swap: a' = [a_lo | b_lo], b' = [a_hi | b_hi] (32-lane rows)
static __device__ __forceinline__ void pswap(u32 &a, u32 &b) {
#if __has_builtin(__builtin_amdgcn_permlane32_swap)
    u32x2 r = __builtin_amdgcn_permlane32_swap(a, b, false, false);
    a = r.x; b = r.y;
#else
    const bool hi = (threadIdx.x & 32) != 0;
    u32 as = (u32)__shfl_xor((int)a, 32, 64);
    u32 bs = (u32)__shfl_xor((int)b, 32, 64);
    u32 na = hi ? bs : a;
    u32 nb = hi ? b  : as;
    a = na; b = nb;
#endif
}

#define MFMA32(a, b, c) __builtin_amdgcn_mfma_f32_32x32x16_bf16(a, b, c, 0, 0, 0)

// exp2 of two key-tiles of one q-tile, tree-sum, pack to bf16, and exchange
// halves in-register so pb[s] is the B-frag for k-step s (replaces Ps LDS
// round-trip: write granules t*4+2h+{0,1}, read granules s*2+h).
static __device__ __forceinline__ float sm_pack(const f32x16 s0, const f32x16 s1,
                                                bf16x8* pb) {
    float p0[16], p1[16];
#pragma unroll
    for (int r = 0; r < 16; ++r) p0[r] = EXP2(s0[r]);
#pragma unroll
    for (int r = 0; r < 16; ++r) p1[r] = EXP2(s1[r]);
    float t0 = (((p0[0] + p0[1]) + (p0[2] + p0[3])) + ((p0[4] + p0[5]) + (p0[6] + p0[7])))
             + (((p0[8] + p0[9]) + (p0[10] + p0[11])) + ((p0[12] + p0[13]) + (p0[14] + p0[15])));
    float t1 = (((p1[0] + p1[1]) + (p1[2] + p1[3])) + ((p1[4] + p1[5]) + (p1[6] + p1[7])))
             + (((p1[8] + p1[9]) + (p1[10] + p1[11])) + ((p1[12] + p1[13]) + (p1[14] + p1[15])));
    uint4 w0, w1, w2, w3;
    w0.x = cvtpk(p0[0], p0[1]);   w0.y = cvtpk(p0[2], p0[3]);
    w0.z = cvtpk(p0[4], p0[5]);   w0.w = cvtpk(p0[6], p0[7]);
    w1.x = cvtpk(p0[8], p0[9]);   w1.y = cvtpk(p0[10], p0[11]);
    w1.z = cvtpk(p0[12], p0[13]); w1.w = cvtpk(p0[14], p0[15]);
    w2.x = cvtpk(p1[0], p1[1]);   w2.y = cvtpk(p1[2], p1[3]);
    w2.z = cvtpk(p1[4], p1[5]);   w2.w = cvtpk(p1[6], p1[7]);
    w3.x = cvtpk(p1[8], p1[9]);   w3.y = cvtpk(p1[10], p1[11]);
    w3.z = cvtpk(p1[12], p1[13]); w3.w = cvtpk(p1[14], p1[15]);
    pswap(w0.x, w1.x); pswap(w0.y, w1.y); pswap(w0.z, w1.z); pswap(w0.w, w1.w);
    pswap(w2.x, w3.x); pswap(w2.y, w3.y); pswap(w2.z, w3.z); pswap(w2.w, w3.w);
    pb[0] = __builtin_bit_cast(bf16x8, w0);
    pb[1] = __builtin_bit_cast(bf16x8, w1);
    pb[2] = __builtin_bit_cast(bf16x8, w2);
    pb[3] = __builtin_bit_cast(bf16x8, w3);
    return t0 + t1;
}

// ============================================================
// W transpose: 96 blocks. W [K=256][N=512] fp32 -> Wt [N][K] bf16 (x3)
// ============================================================
__global__ __launch_bounds__(256)
void wtrans_kernel(const float* __restrict__ Wq, const float* __restrict__ Wk,
                   const float* __restrict__ Wv, u16* __restrict__ Wt)
{
    __shared__ float tile[64 * 65];
    const int bid = blockIdx.x, tid = threadIdx.x;
    const int k0 = (bid & 3) * 64, n0 = ((bid >> 2) & 7) * 64, wsel = bid >> 5;
    const float* W = (wsel == 0) ? Wq : (wsel == 1) ? Wk : Wv;
    u16* Out = Wt + (size_t)wsel * HD * IN_DIM;

    const int r = tid >> 2, c0 = (tid & 3) * 16;
#pragma unroll
    for (int j = 0; j < 16; j += 4) {
        float4 v = *(const float4*)(W + (size_t)(k0 + r) * HD + n0 + c0 + j);
        tile[r * 65 + c0 + j + 0] = v.x; tile[r * 65 + c0 + j + 1] = v.y;
        tile[r * 65 + c0 + j + 2] = v.z; tile[r * 65 + c0 + j + 3] = v.w;
    }
    __syncthreads();
    const int n = tid >> 2, ks = (tid & 3) * 16;
    u16 o[16];
#pragma unroll
    for (int j = 0; j < 16; ++j) o[j] = f2bf(tile[(ks + j) * 65 + n]);
    uint4 u0, u1;
    u0.x = pk(o[0], o[1]);   u0.y = pk(o[2], o[3]);
    u0.z = pk(o[4], o[5]);   u0.w = pk(o[6], o[7]);
    u1.x = pk(o[8], o[9]);   u1.y = pk(o[10], o[11]);
    u1.z = pk(o[12], o[13]); u1.w = pk(o[14], o[15]);
    u16* dst = Out + (size_t)(n0 + n) * IN_DIM + k0 + ks;
    *(uint4*)(dst) = u0;
    *(uint4*)(dst + 8) = u1;
}

// ============================================================
// Fused QKV GEMM + mask build, grid (128, 10):
//  y<8:  GEMM m-tile 64 x head y — 32x32x16 MFMA, acc 48 VGPR,
//        wave w owns (mh=w&1, nh=w>>1) 32x32 tile of Q,K,V.
//  y>=8: adj -> Madd2[q][64*ch + cpos(c)] bf16 {0,-3.39e38}
//        cpos(c) = 32*(c>>5) + 16*((c>>2)&1) + 4*((c>>3)&3) + (c&3)
// ============================================================
__global__ __launch_bounds__(256, 4)
void gemm_mask_kernel(const float* __restrict__ h, const u16* __restrict__ Wt,
                      const int* __restrict__ adj,
                      const float* __restrict__ bq, const float* __restrict__ bk,
                      const float* __restrict__ bv,
                      u16* __restrict__ Qg, u16* __restrict__ Kg,
                      u16* __restrict__ Vtg, u16* __restrict__ Madd2)
{
    __shared__ u16 pool[64 * 64 + 3 * 64 * 64];   // 32 KB
    const int tid = threadIdx.x;

    if (blockIdx.y >= 8) {
        // ---- adjacency -> bf16 additive mask, cpos-permuted cols ----
        int* tile = (int*)pool;              // [64][65] ints
        const int abid = (blockIdx.y - 8) * 128 + blockIdx.x;   // 0..255
        const int tR = abid >> 4, tC = abid & 15;   // q-tile, key-chunk
        const int r = tid >> 2, cg = (tid & 3) * 16;
        const int* src = adj + (size_t)(tR * 64 + r) * NSEQ + tC * 64 + cg;
#pragma unroll
        for (int j = 0; j < 16; j += 4) {
            int4 a = *(const int4*)(src + j);
            tile[r * 65 + cg + j + 0] = a.x; tile[r * 65 + cg + j + 1] = a.y;
            tile[r * 65 + cg + j + 2] = a.z; tile[r * 65 + cg + j + 3] = a.w;
        }
        __syncthreads();
        const int q = tid >> 2, p0 = (tid & 3) * 16;
        u16 o[16];
#pragma unroll
        for (int j = 0; j < 16; ++j) {
            const int p = p0 + j;
            const int c = 32 * (p >> 5) + (p & 3) + 4 * ((p >> 4) & 1) + 8 * ((p >> 2) & 3);
            o[j] = (tile[q * 65 + c] == 0) ? (u16)0xFF7F : (u16)0;
        }
        uint4 u0, u1;
        u0.x = pk(o[0], o[1]);   u0.y = pk(o[2], o[3]);
        u0.z = pk(o[4], o[5]);   u0.w = pk(o[6], o[7]);
        u1.x = pk(o[8], o[9]);   u1.y = pk(o[10], o[11]);
        u1.z = pk(o[12], o[13]); u1.w = pk(o[14], o[15]);
        u16* dst = Madd2 + (size_t)(tR * 64 + q) * NSEQ + tC * 64 + p0;
        *(uint4*)(dst) = u0;
        *(uint4*)(dst + 8) = u1;
        return;
    }

    // ---------------- GEMM branch (32x32x16) ----------------
    u16* As = pool;
    u16* Bs = pool + 64 * 64;

    const int m0 = blockIdx.x * 64;
    const int hh = blockIdx.y;
    const int n0 = hh * 64;

    const int w = tid >> 6, lane = tid & 63;
    const int l31 = lane & 31, half = lane >> 5;
    const int mh = w & 1, nh = w >> 1;
    const int s7 = l31 & 7;

    f32x16 acc[3] = {};   // Q, K, V 32x32 tiles

    const int arw = tid >> 2, acg = (tid & 3) * 2;
    const int brw = tid & 63, bgrp = tid >> 6;
    const float* srcA = h + (size_t)(m0 + arw) * IN_DIM;

    for (int kk = 0; kk < IN_DIM; kk += 64) {
        __syncthreads();
#pragma unroll
        for (int g = 0; g < 2; ++g) {
            const float* p = srcA + kk + (acg + g) * 8;
            float4 v0 = *(const float4*)(p);
            float4 v1 = *(const float4*)(p + 4);
            uint4 u;
            u.x = cvtpk(v0.x, v0.y); u.y = cvtpk(v0.z, v0.w);
            u.z = cvtpk(v1.x, v1.y); u.w = cvtpk(v1.z, v1.w);
            *(uint4*)&As[arw * 64 + (((acg + g) ^ (arw & 7)) * 8)] = u;
        }
#pragma unroll
        for (int i = 0; i < 6; ++i) {
            const int gc = bgrp * 6 + i;
            const int wh = gc >> 3, c8 = gc & 7;
            *(uint4*)&Bs[wh * 4096 + brw * 64 + ((c8 ^ (brw & 7)) * 8)] =
                *(const uint4*)(Wt + (size_t)wh * HD * IN_DIM +
                                (size_t)(n0 + brw) * IN_DIM + kk + c8 * 8);
        }
        __syncthreads();
        const int arow = (32 * mh + l31) * 64;
        const int brow = (32 * nh + l31) * 64;
#pragma unroll
        for (int s = 0; s < 4; ++s) {
            const int g = ((s * 2 + half) ^ s7) * 8;
            bf16x8 a = *(const bf16x8*)&As[arow + g];
#pragma unroll
            for (int wh = 0; wh < 3; ++wh) {
                bf16x8 b = *(const bf16x8*)&Bs[wh * 4096 + brow + g];
                acc[wh] = __builtin_amdgcn_mfma_f32_32x32x16_bf16(a, b, acc[wh], 0, 0, 0);
            }
        }
    }

    // ---- Q and K epilogues: LDS re-tile, coalesced stores ----
    // C-layout: col = 32*nh + l31, row = 32*mh + 4*half + (r&3) + 8*(r>>2)
    for (int which = 0; which < 2; ++which) {
        u16* T = pool;   // [64][72]
        const float* bias = (which == 0) ? bq : bk;
        u16* Out = (which == 0) ? Qg : Kg;
        const float scale = (which == 0) ? QSCALE : 1.0f;
        const float bvv = bias[n0 + 32 * nh + l31];
        __syncthreads();
#pragma unroll
        for (int r = 0; r < 16; ++r) {
            const int row = 32 * mh + 4 * half + (r & 3) + 8 * (r >> 2);
            T[row * 72 + 32 * nh + l31] = f2bf((acc[which][r] + bvv) * scale);
        }
        __syncthreads();
        const int row = tid >> 2, qc = (tid & 3) * 16;
        u16* dst = Out + (size_t)(m0 + row) * HD + n0 + qc;
        const u16* srcT = &T[row * 72 + qc];
        *(uint4*)(dst)     = *(const uint4*)(srcT);
        *(uint4*)(dst + 8) = *(const uint4*)(srcT + 8);
    }

    // ---- V epilogue: transpose + cpos permutation ----
    // m = 32*mh + 4*half + (r&3) + 8*(r>>2)  ->  pos(m) = 32*mh + 16*half + 4*(r>>2) + (r&3)
    {
        u16* T = pool;   // [64][72]  [d][pos]
        const int d = 32 * nh + l31;
        const float bvv = bv[n0 + d];
        __syncthreads();
#pragma unroll
        for (int g = 0; g < 4; ++g) {
            ushort4 o;
            o.x = f2bf(acc[2][4 * g + 0] + bvv);
            o.y = f2bf(acc[2][4 * g + 1] + bvv);
            o.z = f2bf(acc[2][4 * g + 2] + bvv);
            o.w = f2bf(acc[2][4 * g + 3] + bvv);
            *(ushort4*)&T[d * 72 + 32 * mh + 16 * half + 4 * g] = o;
        }
        __syncthreads();
        const int b = m0 >> 10, nloc = m0 & 1023;
        const int dd = tid >> 2, c = (tid & 3) * 16;
        u16* dst = Vtg + ((size_t)(b * NHEADS + hh) * DH + dd) * NSEQ + nloc + c;
        *(uint4*)(dst)     = *(uint4*)&T[dd * 72 + c];
        *(uint4*)(dst + 8) = *(uint4*)&T[dd * 72 + c + 8];
    }
}

// ============================================================
// Fused masked attention, 32x32x16 MFMA, no-max softmax.
// qrep=2 (64 q/wave) for LDS A-frag amortization + key-split teams for
// occupancy: 8 waves/block (512 thr), waves 0-3 = team 0 (key chunks
// 0-7), waves 4-7 = team 1 (chunks 8-15); partial O/l summed via LDS
// at the end (no-max softmax => partials add). grid (64 bh, 4 qt) =
// 256 blocks, 1 block/CU, 2 waves/SIMD. P stays in registers via
// permlane32_swap; K/V prefetch distance 2 per team.
// ============================================================
__global__ __launch_bounds__(512, 2)
void attn_kernel(const u16* __restrict__ Madd2, const u16* __restrict__ Qg,
                 const u16* __restrict__ Kg, const u16* __restrict__ Vtg,
                 float* __restrict__ out)
{
    __shared__ __align__(16) u16 Ks[2][2][64 * 64];   // [team][buf] 32 KB
    __shared__ __align__(16) u16 Vs[2][2][64 * 64];   // 32 KB  [d][cpos(m)]

    const int tid = threadIdx.x;
    const int w = tid >> 6, lane = tid & 63;
    const int team = w >> 2, wq = w & 3;
    const int l31 = lane & 31, half = lane >> 5;
    const int bh = blockIdx.x, qt = blockIdx.y;
    const int b = bh >> 3;
    const int n0 = qt * 256;
    const size_t rowbase = (size_t)b * NSEQ;
    const int colbase = (bh & 7) * DH;
    const int q7 = l31 & 7;
    const int qA = wq * 64 + l31;         // block-local q row, tile A
    const int qB = qA + 32;               // tile B
    const int cbase = team * 8;           // team's first key chunk

    // Q B-frags (bf16, pre-scaled): B[k][q=l31]
    const u16* qga = Qg + (rowbase + n0 + qA) * HD + colbase;
    const u16* qgb = Qg + (rowbase + n0 + qB) * HD + colbase;
    bf16x8 qbA[4], qbB[4];
#pragma unroll
    for (int s = 0; s < 4; ++s) {
        qbA[s] = *(const bf16x8*)(qga + s * 16 + half * 8);
        qbB[s] = *(const bf16x8*)(qgb + s * 16 + half * 8);
    }

    // staging: 256 thr per team -> 64 rows x 4 granule-pairs of K and V
    const int ttid = tid & 255;
    const int srow = ttid >> 2, cp = (ttid & 3) * 2;
    const int swc0 = ((cp ^ (srow & 7)) * 8), swc1 = (((cp + 1) ^ (srow & 7)) * 8);
    const u16* kgp = Kg + (rowbase + srow) * HD + colbase + cp * 8 +
                     (size_t)cbase * 64 * HD;
    const u16* vgp = Vtg + ((size_t)bh * DH + srow) * NSEQ + cp * 8 + cbase * 64;
    // mask rows (cols cpos-permuted): lane's own two q rows, team's chunks
    const u16* mrowA = Madd2 + (size_t)(n0 + qA) * NSEQ + half * 16 + cbase * 64;
    const u16* mrowB = Madd2 + (size_t)(n0 + qB) * NSEQ + half * 16 + cbase * 64;

    // mask regs, team-chunk 0
    uint4 mA0a = *(const uint4*)(mrowA);
    uint4 mA0b = *(const uint4*)(mrowA + 8);
    uint4 mA1a = *(const uint4*)(mrowA + 32);
    uint4 mA1b = *(const uint4*)(mrowA + 40);
    uint4 mB0a = *(const uint4*)(mrowB);
    uint4 mB0b = *(const uint4*)(mrowB + 8);
    uint4 mB1a = *(const uint4*)(mrowB + 32);
    uint4 mB1b = *(const uint4*)(mrowB + 40);

    // K/V reg sets: s0 holds team-chunk 0 (staged immediately), s1 chunk 1
    uint4 s0k0, s0k1, s0v0, s0v1;
    uint4 s1k0, s1k1, s1v0, s1v1;
    s0k0 = *(const uint4*)kgp;       s0k1 = *(const uint4*)(kgp + 8);
    s0v0 = *(const uint4*)vgp;       s0v1 = *(const uint4*)(vgp + 8);
    *(uint4*)&Ks[team][0][srow * 64 + swc0] = s0k0;
    *(uint4*)&Ks[team][0][srow * 64 + swc1] = s0k1;
    *(uint4*)&Vs[team][0][srow * 64 + swc0] = s0v0;
    *(uint4*)&Vs[team][0][srow * 64 + swc1] = s0v1;
    s1k0 = *(const uint4*)(kgp + (size_t)64 * HD);
    s1k1 = *(const uint4*)(kgp + (size_t)64 * HD + 8);
    s1v0 = *(const uint4*)(vgp + 64);
    s1v1 = *(const uint4*)(vgp + 64 + 8);
    __syncthreads();

    float lA = 0.f, lB = 0.f;
    f32x16 OA0 = {}, OA1 = {}, OB0 = {}, OB1 = {};

#define CHUNK(CH, CUR, KW, KL)                                                 \
    {                                                                          \
        f32x16 sA0 = maskinit(mA0a, mA0b);                                     \
        f32x16 sA1 = maskinit(mA1a, mA1b);                                     \
        f32x16 sB0 = maskinit(mB0a, mB0b);                                     \
        f32x16 sB1 = maskinit(mB1a, mB1b);                                     \
        if ((CH) < 7) {                                                        \
            const u16* ma = mrowA + ((CH) + 1) * 64;                           \
            const u16* mb = mrowB + ((CH) + 1) * 64;                           \
            mA0a = *(const uint4*)(ma);      mA0b = *(const uint4*)(ma + 8);   \
            mA1a = *(const uint4*)(ma + 32); mA1b = *(const uint4*)(ma + 40);  \
            mB0a = *(const uint4*)(mb);      mB0b = *(const uint4*)(mb + 8);   \
            mB1a = *(const uint4*)(mb + 32); mB1b = *(const uint4*)(mb + 40);  \
        }                                                                      \
        _Pragma("unroll")                                                      \
        for (int s = 0; s < 4; ++s) {                                          \
            const int g = ((s * 2 + half) ^ q7) * 8;                           \
            bf16x8 ka0 = *(const bf16x8*)&Ks[team][CUR][l31 * 64 + g];         \
            bf16x8 ka1 = *(const bf16x8*)&Ks[team][CUR][(32 + l31) * 64 + g];  \
            sA0 = MFMA32(ka0, qbA[s], sA0);                                    \
            sA1 = MFMA32(ka1, qbA[s], sA1);                                    \
            sB0 = MFMA32(ka0, qbB[s], sB0);                                    \
            sB1 = MFMA32(ka1, qbB[s], sB1);                                    \
        }                                                                      \
        if ((CH) < 7) {                                                        \
            *(uint4*)&Ks[team][1 - (CUR)][srow * 64 + swc0] = KW##k0;          \
            *(uint4*)&Ks[team][1 - (CUR)][srow * 64 + swc1] = KW##k1;          \
            *(uint4*)&Vs[team][1 - (CUR)][srow * 64 + swc0] = KW##v0;          \
            *(uint4*)&Vs[team][1 - (CUR)][srow * 64 + swc1] = KW##v1;          \
        }                                                                      \
        if ((CH) < 6) {                                                        \
            const size_t ko = (size_t)((CH) + 2) * 64 * HD;                    \
            const int    vo = ((CH) + 2) * 64;                                 \
            KL##k0 = *(const uint4*)(kgp + ko);                                \
            KL##k1 = *(const uint4*)(kgp + ko + 8);                            \
            KL##v0 = *(const uint4*)(vgp + vo);                                \
            KL##v1 = *(const uint4*)(vgp + vo + 8);                            \
        }                                                                      \
        bf16x8 pbA[4], pbB[4];                                                 \
        lA += sm_pack(sA0, sA1, pbA);                                          \
        lB += sm_pack(sB0, sB1, pbB);                                          \
        _Pragma("unroll")                                                      \
        for (int s = 0; s < 4; ++s) {                                          \
            const int g = ((s * 2 + half) ^ q7) * 8;                           \
            bf16x8 va0 = *(const bf16x8*)&Vs[team][CUR][l31 * 64 + g];         \
            bf16x8 va1 = *(const bf16x8*)&Vs[team][CUR][(32 + l31) * 64 + g];  \
            OA0 = MFMA32(va0, pbA[s], OA0);                                    \
            OA1 = MFMA32(va1, pbA[s], OA1);                                    \
            OB0 = MFMA32(va0, pbB[s], OB0);                                    \
            OB1 = MFMA32(va1, pbB[s], OB1);                                    \
        }                                                                      \
        __syncthreads();                                                       \
    }

    for (int ch = 0; ch < 8; ch += 2) {
        CHUNK(ch,     0, s1, s0)
        CHUNK(ch + 1, 1, s0, s1)
    }
#undef CHUNK

    // ---- cross-team combine: no-max softmax => partials just add ----
    // Overlay the dead K/V buffers: Oex = 32 KB (one 8-group round),
    // Lex in Vs region. Two rounds: {OA0,OA1} then {OB0,OB1}.
    float4* Oex = (float4*)&Ks[0][0][0];   // 2048 float4 = 32 KB
    float*  Lex = (float*)&Vs[0][0][0];

    if (team == 1) {
#pragma unroll
        for (int g = 0; g < 4; ++g) {
            float4 t0, t1;
            t0.x = OA0[4 * g + 0]; t0.y = OA0[4 * g + 1];
            t0.z = OA0[4 * g + 2]; t0.w = OA0[4 * g + 3];
            t1.x = OA1[4 * g + 0]; t1.y = OA1[4 * g + 1];
            t1.z = OA1[4 * g + 2]; t1.w = OA1[4 * g + 3];
            Oex[(wq * 8 + g) * 64 + lane]     = t0;
            Oex[(wq * 8 + 4 + g) * 64 + lane] = t1;
        }
        Lex[wq * 128 + lane]      = lA;
        Lex[wq * 128 + 64 + lane] = lB;
    }
    __syncthreads();
    if (team == 0) {
        lA += Lex[wq * 128 + lane];
        lB += Lex[wq * 128 + 64 + lane];
#pragma unroll
        for (int g = 0; g < 4; ++g) {
            float4 t0 = Oex[(wq * 8 + g) * 64 + lane];
            float4 t1 = Oex[(wq * 8 + 4 + g) * 64 + lane];
            OA0[4 * g + 0] += t0.x; OA0[4 * g + 1] += t0.y;
            OA0[4 * g + 2] += t0.z; OA0[4 * g + 3] += t0.w;
            OA1[4 * g + 0] += t1.x; OA1[4 * g + 1] += t1.y;
            OA1[4 * g + 2] += t1.z; OA1[4 * g + 3] += t1.w;
        }
    }
    __syncthreads();
    if (team == 1) {
#pragma unroll
        for (int g = 0; g < 4; ++g) {
            float4 t0, t1;
            t0.x = OB0[4 * g + 0]; t0.y = OB0[4 * g + 1];
            t0.z = OB0[4 * g + 2]; t0.w = OB0[4 * g + 3];
            t1.x = OB1[4 * g + 0]; t1.y = OB1[4 * g + 1];
            t1.z = OB1[4 * g + 2]; t1.w = OB1[4 * g + 3];
            Oex[(wq * 8 + g) * 64 + lane]     = t0;
            Oex[(wq * 8 + 4 + g) * 64 + lane] = t1;
        }
    }
    __syncthreads();
    if (team == 0) {
#pragma unroll
        for (int g = 0; g < 4; ++g) {
            float4 t0 = Oex[(wq * 8 + g) * 64 + lane];
            float4 t1 = Oex[(wq * 8 + 4 + g) * 64 + lane];
            OB0[4 * g + 0] += t0.x; OB0[4 * g + 1] += t0.y;
            OB0[4 * g + 2] += t0.z; OB0[4 * g + 3] += t0.w;
            OB1[4 * g + 0] += t1.x; OB1[4 * g + 1] += t1.y;
            OB1[4 * g + 2] += t1.z; OB1[4 * g + 3] += t1.w;
        }

        // l: lanes l and l+32 hold disjoint key subsets of the same q
        lA += __shfl_xor(lA, 32, 64);
        lB += __shfl_xor(lB, 32, 64);
        const float invA = 1.0f / lA;
        const float invB = 1.0f / lB;

        float* orowA = out + (rowbase + n0 + qA) * HD + colbase;
        float* orowB = out + (rowbase + n0 + qB) * HD + colbase;
#pragma unroll
        for (int g = 0; g < 4; ++g) {
            const int d0 = 4 * half + 8 * g;
            float4 a0, a1, b0, b1;
            a0.x = OA0[4 * g + 0] * invA; a0.y = OA0[4 * g + 1] * invA;
            a0.z = OA0[4 * g + 2] * invA; a0.w = OA0[4 * g + 3] * invA;
            a1.x = OA1[4 * g + 0] * invA; a1.y = OA1[4 * g + 1] * invA;
            a1.z = OA1[4 * g + 2] * invA; a1.w = OA1[4 * g + 3] * invA;
            b0.x = OB0[4 * g + 0] * invB; b0.y = OB0[4 * g + 1] * invB;
            b0.z = OB0[4 * g + 2] * invB; b0.w = OB0[4 * g + 3] * invB;
            b1.x = OB1[4 * g + 0] * invB; b1.y = OB1[4 * g + 1] * invB;
            b1.z = OB1[4 * g + 2] * invB; b1.w = OB1[4 * g + 3] * invB;
            *(float4*)(orowA + d0)      = a0;
            *(float4*)(orowA + 32 + d0) = a1;
            *(float4*)(orowB + d0)      = b0;
            *(float4*)(orowB + 32 + d0) = b1;
        }
    }
}

// ============================================================
extern "C" void kernel_launch(void* const* d_in, const int* in_sizes, int n_in,
                              void* d_out, int out_size, void* d_ws, size_t ws_size,
                              hipStream_t stream) {
    const int*   adj = (const int*)d_in[0];
    const float* h   = (const float*)d_in[1];
    const float* Wq  = (const float*)d_in[2];
    const float* bq  = (const float*)d_in[3];
    const float* Wk  = (const float*)d_in[4];
    const float* bk  = (const float*)d_in[5];
    const float* Wv  = (const float*)d_in[6];
    const float* bv  = (const float*)d_in[7];
    float* outp = (float*)d_out;

    u16* Wt    = (u16*)d_ws;                                 // 3*512*256 u16
    u16* Qg    = Wt + (size_t)3 * HD * IN_DIM;               // 4 Mi u16 each
    u16* Kg    = Qg + (size_t)BATCH * NSEQ * HD;
    u16* Vtg   = Kg + (size_t)BATCH * NSEQ * HD;
    u16* Madd2 = Vtg + (size_t)BATCH * NSEQ * HD;            // 1 Mi u16
    (void)ws_size;

    wtrans_kernel<<<96, 256, 0, stream>>>(Wq, Wk, Wv, Wt);
    gemm_mask_kernel<<<dim3(BATCH * NSEQ / 64, 10), 256, 0, stream>>>(
        h, Wt, adj, bq, bk, bv, Qg, Kg, Vtg, Madd2);
    attn_kernel<<<dim3(BATCH * NHEADS, NSEQ / 256), 512, 0, stream>>>(
        Madd2, Qg, Kg, Vtg, outp);
}

// Round 3
// 184.492 us; speedup vs baseline: 1.0023x; 1.0023x over previous
//
#include <hip/hip_runtime.h>
#include <hip/hip_bf16.h>
#include <math.h>

#define IN_DIM 256
#define HD     512   // NUM_HEADS * OUT_DIM
#define NHEADS 8
#define DH     64
#define NSEQ   1024
#define BATCH  8

#define QSCALE 0.18033688011112042f   // 0.125 * log2(e): S in log2 domain

typedef unsigned short u16;
typedef unsigned int   u32;
typedef short bf16x8 __attribute__((ext_vector_type(8)));
typedef float f32x4  __attribute__((ext_vector_type(4)));
typedef float f32x16 __attribute__((ext_vector_type(16)));
typedef unsigned int u32x2 __attribute__((ext_vector_type(2)));

#if __has_builtin(__builtin_amdgcn_exp2f)
#define EXP2(x) __builtin_amdgcn_exp2f(x)
#else
#define EXP2(x) __expf(0.69314718056f * (x))
#endif

static __device__ __forceinline__ u16 f2bf(float x) {
    u32 u = __builtin_bit_cast(u32, x);
    u += 0x7FFFu + ((u >> 16) & 1u);     // RNE
    return (u16)(u >> 16);
}
static __device__ __forceinline__ u32 pk(u16 a, u16 b) {
    return (u32)a | ((u32)b << 16);
}
static __device__ __forceinline__ u32 cvtpk(float a, float b) {
    __hip_bfloat162 t = __float22bfloat162_rn(make_float2(a, b));
    u32 r; __builtin_memcpy(&r, &t, 4);
    return r;
}
// 16 bf16 (two uint4) -> f32x16 C-init
static __device__ __forceinline__ f32x16 maskinit(uint4 a, uint4 b) {
    f32x16 c;
    u32 ws[8] = {a.x, a.y, a.z, a.w, b.x, b.y, b.z, b.w};
#pragma unroll
    for (int i = 0; i < 8; ++i) {
        c[2 * i]     = __builtin_bit_cast(float, ws[i] << 16);
        c[2 * i + 1] = __builtin_bit_cast(float, ws[i] & 0xFFFF0000u);
    }
    return c;
}

// permlane32_swap: a' = [a_lo | b_lo], b' = [a_hi | b_hi] (32-lane rows)
static __device__ __forceinline__ void pswap(u32 &a, u32 &b) {
#if __has_builtin(__builtin_amdgcn_permlane32_swap)
    u32x2 r = __builtin_amdgcn_permlane32_swap(a, b, false, false);
    a = r.x; b = r.y;
#else
    const bool hi = (threadIdx.x & 32) != 0;
    u32 as = (u32)__shfl_xor((int)a, 32, 64);
    u32 bs = (u32)__shfl_xor((int)b, 32, 64);
    u32 na = hi ? bs : a;
    u32 nb = hi ? b  : as;
    a = na; b = nb;
#endif
}

#define MFMA32(a, b, c) __builtin_amdgcn_mfma_f32_32x32x16_bf16(a, b, c, 0, 0, 0)

// exp2 of two key-tiles of one q-tile, tree-sum, pack to bf16, and exchange
// halves in-register so pb[s] is the B-frag for k-step s (replaces Ps LDS
// round-trip: write granules t*4+2h+{0,1}, read granules s*2+h).
static __device__ __forceinline__ float sm_pack(const f32x16 s0, const f32x16 s1,
                                                bf16x8* pb) {
    float p0[16], p1[16];
#pragma unroll
    for (int r = 0; r < 16; ++r) p0[r] = EXP2(s0[r]);
#pragma unroll
    for (int r = 0; r < 16; ++r) p1[r] = EXP2(s1[r]);
    float t0 = (((p0[0] + p0[1]) + (p0[2] + p0[3])) + ((p0[4] + p0[5]) + (p0[6] + p0[7])))
             + (((p0[8] + p0[9]) + (p0[10] + p0[11])) + ((p0[12] + p0[13]) + (p0[14] + p0[15])));
    float t1 = (((p1[0] + p1[1]) + (p1[2] + p1[3])) + ((p1[4] + p1[5]) + (p1[6] + p1[7])))
             + (((p1[8] + p1[9]) + (p1[10] + p1[11])) + ((p1[12] + p1[13]) + (p1[14] + p1[15])));
    uint4 w0, w1, w2, w3;
    w0.x = cvtpk(p0[0], p0[1]);   w0.y = cvtpk(p0[2], p0[3]);
    w0.z = cvtpk(p0[4], p0[5]);   w0.w = cvtpk(p0[6], p0[7]);
    w1.x = cvtpk(p0[8], p0[9]);   w1.y = cvtpk(p0[10], p0[11]);
    w1.z = cvtpk(p0[12], p0[13]); w1.w = cvtpk(p0[14], p0[15]);
    w2.x = cvtpk(p1[0], p1[1]);   w2.y = cvtpk(p1[2], p1[3]);
    w2.z = cvtpk(p1[4], p1[5]);   w2.w = cvtpk(p1[6], p1[7]);
    w3.x = cvtpk(p1[8], p1[9]);   w3.y = cvtpk(p1[10], p1[11]);
    w3.z = cvtpk(p1[12], p1[13]); w3.w = cvtpk(p1[14], p1[15]);
    pswap(w0.x, w1.x); pswap(w0.y, w1.y); pswap(w0.z, w1.z); pswap(w0.w, w1.w);
    pswap(w2.x, w3.x); pswap(w2.y, w3.y); pswap(w2.z, w3.z); pswap(w2.w, w3.w);
    pb[0] = __builtin_bit_cast(bf16x8, w0);
    pb[1] = __builtin_bit_cast(bf16x8, w1);
    pb[2] = __builtin_bit_cast(bf16x8, w2);
    pb[3] = __builtin_bit_cast(bf16x8, w3);
    return t0 + t1;
}

// ============================================================
// W transpose: 96 blocks. W [K=256][N=512] fp32 -> Wt [N][K] bf16 (x3)
// ============================================================
__global__ __launch_bounds__(256)
void wtrans_kernel(const float* __restrict__ Wq, const float* __restrict__ Wk,
                   const float* __restrict__ Wv, u16* __restrict__ Wt)
{
    __shared__ float tile[64 * 65];
    const int bid = blockIdx.x, tid = threadIdx.x;
    const int k0 = (bid & 3) * 64, n0 = ((bid >> 2) & 7) * 64, wsel = bid >> 5;
    const float* W = (wsel == 0) ? Wq : (wsel == 1) ? Wk : Wv;
    u16* Out = Wt + (size_t)wsel * HD * IN_DIM;

    const int r = tid >> 2, c0 = (tid & 3) * 16;
#pragma unroll
    for (int j = 0; j < 16; j += 4) {
        float4 v = *(const float4*)(W + (size_t)(k0 + r) * HD + n0 + c0 + j);
        tile[r * 65 + c0 + j + 0] = v.x; tile[r * 65 + c0 + j + 1] = v.y;
        tile[r * 65 + c0 + j + 2] = v.z; tile[r * 65 + c0 + j + 3] = v.w;
    }
    __syncthreads();
    const int n = tid >> 2, ks = (tid & 3) * 16;
    u16 o[16];
#pragma unroll
    for (int j = 0; j < 16; ++j) o[j] = f2bf(tile[(ks + j) * 65 + n]);
    uint4 u0, u1;
    u0.x = pk(o[0], o[1]);   u0.y = pk(o[2], o[3]);
    u0.z = pk(o[4], o[5]);   u0.w = pk(o[6], o[7]);
    u1.x = pk(o[8], o[9]);   u1.y = pk(o[10], o[11]);
    u1.z = pk(o[12], o[13]); u1.w = pk(o[14], o[15]);
    u16* dst = Out + (size_t)(n0 + n) * IN_DIM + k0 + ks;
    *(uint4*)(dst) = u0;
    *(uint4*)(dst + 8) = u1;
}

// ============================================================
// Fused QKV GEMM + mask build, grid (128, 10):
//  y<8:  GEMM m-tile 64 x head y — 32x32x16 MFMA, acc 48 VGPR,
//        wave w owns (mh=w&1, nh=w>>1) 32x32 tile of Q,K,V.
//  y>=8: adj -> Madd2[q][64*ch + cpos(c)] bf16 {0,-3.39e38}
//        cpos(c) = 32*(c>>5) + 16*((c>>2)&1) + 4*((c>>3)&3) + (c&3)
// ============================================================
__global__ __launch_bounds__(256, 4)
void gemm_mask_kernel(const float* __restrict__ h, const u16* __restrict__ Wt,
                      const int* __restrict__ adj,
                      const float* __restrict__ bq, const float* __restrict__ bk,
                      const float* __restrict__ bv,
                      u16* __restrict__ Qg, u16* __restrict__ Kg,
                      u16* __restrict__ Vtg, u16* __restrict__ Madd2)
{
    __shared__ u16 pool[64 * 64 + 3 * 64 * 64];   // 32 KB
    const int tid = threadIdx.x;

    if (blockIdx.y >= 8) {
        // ---- adjacency -> bf16 additive mask, cpos-permuted cols ----
        int* tile = (int*)pool;              // [64][65] ints
        const int abid = (blockIdx.y - 8) * 128 + blockIdx.x;   // 0..255
        const int tR = abid >> 4, tC = abid & 15;   // q-tile, key-chunk
        const int r = tid >> 2, cg = (tid & 3) * 16;
        const int* src = adj + (size_t)(tR * 64 + r) * NSEQ + tC * 64 + cg;
#pragma unroll
        for (int j = 0; j < 16; j += 4) {
            int4 a = *(const int4*)(src + j);
            tile[r * 65 + cg + j + 0] = a.x; tile[r * 65 + cg + j + 1] = a.y;
            tile[r * 65 + cg + j + 2] = a.z; tile[r * 65 + cg + j + 3] = a.w;
        }
        __syncthreads();
        const int q = tid >> 2, p0 = (tid & 3) * 16;
        u16 o[16];
#pragma unroll
        for (int j = 0; j < 16; ++j) {
            const int p = p0 + j;
            const int c = 32 * (p >> 5) + (p & 3) + 4 * ((p >> 4) & 1) + 8 * ((p >> 2) & 3);
            o[j] = (tile[q * 65 + c] == 0) ? (u16)0xFF7F : (u16)0;
        }
        uint4 u0, u1;
        u0.x = pk(o[0], o[1]);   u0.y = pk(o[2], o[3]);
        u0.z = pk(o[4], o[5]);   u0.w = pk(o[6], o[7]);
        u1.x = pk(o[8], o[9]);   u1.y = pk(o[10], o[11]);
        u1.z = pk(o[12], o[13]); u1.w = pk(o[14], o[15]);
        u16* dst = Madd2 + (size_t)(tR * 64 + q) * NSEQ + tC * 64 + p0;
        *(uint4*)(dst) = u0;
        *(uint4*)(dst + 8) = u1;
        return;
    }

    // ---------------- GEMM branch (32x32x16) ----------------
    u16* As = pool;
    u16* Bs = pool + 64 * 64;

    const int m0 = blockIdx.x * 64;
    const int hh = blockIdx.y;
    const int n0 = hh * 64;

    const int w = tid >> 6, lane = tid & 63;
    const int l31 = lane & 31, half = lane >> 5;
    const int mh = w & 1, nh = w >> 1;
    const int s7 = l31 & 7;

    f32x16 acc[3] = {};   // Q, K, V 32x32 tiles

    const int arw = tid >> 2, acg = (tid & 3) * 2;
    const int brw = tid & 63, bgrp = tid >> 6;
    const float* srcA = h + (size_t)(m0 + arw) * IN_DIM;

    for (int kk = 0; kk < IN_DIM; kk += 64) {
        __syncthreads();
#pragma unroll
        for (int g = 0; g < 2; ++g) {
            const float* p = srcA + kk + (acg + g) * 8;
            float4 v0 = *(const float4*)(p);
            float4 v1 = *(const float4*)(p + 4);
            uint4 u;
            u.x = cvtpk(v0.x, v0.y); u.y = cvtpk(v0.z, v0.w);
            u.z = cvtpk(v1.x, v1.y); u.w = cvtpk(v1.z, v1.w);
            *(uint4*)&As[arw * 64 + (((acg + g) ^ (arw & 7)) * 8)] = u;
        }
#pragma unroll
        for (int i = 0; i < 6; ++i) {
            const int gc = bgrp * 6 + i;
            const int wh = gc >> 3, c8 = gc & 7;
            *(uint4*)&Bs[wh * 4096 + brw * 64 + ((c8 ^ (brw & 7)) * 8)] =
                *(const uint4*)(Wt + (size_t)wh * HD * IN_DIM +
                                (size_t)(n0 + brw) * IN_DIM + kk + c8 * 8);
        }
        __syncthreads();
        const int arow = (32 * mh + l31) * 64;
        const int brow = (32 * nh + l31) * 64;
#pragma unroll
        for (int s = 0; s < 4; ++s) {
            const int g = ((s * 2 + half) ^ s7) * 8;
            bf16x8 a = *(const bf16x8*)&As[arow + g];
#pragma unroll
            for (int wh = 0; wh < 3; ++wh) {
                bf16x8 b = *(const bf16x8*)&Bs[wh * 4096 + brow + g];
                acc[wh] = __builtin_amdgcn_mfma_f32_32x32x16_bf16(a, b, acc[wh], 0, 0, 0);
            }
        }
    }

    // ---- Q and K epilogues: LDS re-tile, coalesced stores ----
    // C-layout: col = 32*nh + l31, row = 32*mh + 4*half + (r&3) + 8*(r>>2)
    for (int which = 0; which < 2; ++which) {
        u16* T = pool;   // [64][72]
        const float* bias = (which == 0) ? bq : bk;
        u16* Out = (which == 0) ? Qg : Kg;
        const float scale = (which == 0) ? QSCALE : 1.0f;
        const float bvv = bias[n0 + 32 * nh + l31];
        __syncthreads();
#pragma unroll
        for (int r = 0; r < 16; ++r) {
            const int row = 32 * mh + 4 * half + (r & 3) + 8 * (r >> 2);
            T[row * 72 + 32 * nh + l31] = f2bf((acc[which][r] + bvv) * scale);
        }
        __syncthreads();
        const int row = tid >> 2, qc = (tid & 3) * 16;
        u16* dst = Out + (size_t)(m0 + row) * HD + n0 + qc;
        const u16* srcT = &T[row * 72 + qc];
        *(uint4*)(dst)     = *(const uint4*)(srcT);
        *(uint4*)(dst + 8) = *(const uint4*)(srcT + 8);
    }

    // ---- V epilogue: transpose + cpos permutation ----
    // m = 32*mh + 4*half + (r&3) + 8*(r>>2)  ->  pos(m) = 32*mh + 16*half + 4*(r>>2) + (r&3)
    {
        u16* T = pool;   // [64][72]  [d][pos]
        const int d = 32 * nh + l31;
        const float bvv = bv[n0 + d];
        __syncthreads();
#pragma unroll
        for (int g = 0; g < 4; ++g) {
            ushort4 o;
            o.x = f2bf(acc[2][4 * g + 0] + bvv);
            o.y = f2bf(acc[2][4 * g + 1] + bvv);
            o.z = f2bf(acc[2][4 * g + 2] + bvv);
            o.w = f2bf(acc[2][4 * g + 3] + bvv);
            *(ushort4*)&T[d * 72 + 32 * mh + 16 * half + 4 * g] = o;
        }
        __syncthreads();
        const int b = m0 >> 10, nloc = m0 & 1023;
        const int dd = tid >> 2, c = (tid & 3) * 16;
        u16* dst = Vtg + ((size_t)(b * NHEADS + hh) * DH + dd) * NSEQ + nloc + c;
        *(uint4*)(dst)     = *(uint4*)&T[dd * 72 + c];
        *(uint4*)(dst + 8) = *(uint4*)&T[dd * 72 + c + 8];
    }
}

// ============================================================
// Fused masked attention, 32x32x16 MFMA, no-max softmax.
// qrep=2 (64 q/wave) for LDS A-frag amortization + key-split teams for
// occupancy: 8 waves/block (512 thr), waves 0-3 = team 0 (key chunks
// 0-7), waves 4-7 = team 1 (chunks 8-15); partial O/l summed via LDS
// at the end. grid (64 bh, 4 qt) = 256 blocks, 1 block/CU, 2 waves/SIMD.
// launch_bounds(512, 1): round-2's (512,2) capped VGPR at 128 ->
// ~270 MB scratch spill traffic (WRITE_SIZE 155 MB vs 16 MB output).
// Per-wave state needs ~212 VGPR; <=256 still gives 8 waves/CU.
// ============================================================
__global__ __launch_bounds__(512, 1)
void attn_kernel(const u16* __restrict__ Madd2, const u16* __restrict__ Qg,
                 const u16* __restrict__ Kg, const u16* __restrict__ Vtg,
                 float* __restrict__ out)
{
    __shared__ __align__(16) u16 Ks[2][2][64 * 64];   // [team][buf] 32 KB
    __shared__ __align__(16) u16 Vs[2][2][64 * 64];   // 32 KB  [d][cpos(m)]

    const int tid = threadIdx.x;
    const int w = tid >> 6, lane = tid & 63;
    const int team = w >> 2, wq = w & 3;
    const int l31 = lane & 31, half = lane >> 5;
    const int bh = blockIdx.x, qt = blockIdx.y;
    const int b = bh >> 3;
    const int n0 = qt * 256;
    const size_t rowbase = (size_t)b * NSEQ;
    const int colbase = (bh & 7) * DH;
    const int q7 = l31 & 7;
    const int qA = wq * 64 + l31;         // block-local q row, tile A
    const int qB = qA + 32;               // tile B
    const int cbase = team * 8;           // team's first key chunk

    // Q B-frags (bf16, pre-scaled): B[k][q=l31]
    const u16* qga = Qg + (rowbase + n0 + qA) * HD + colbase;
    const u16* qgb = Qg + (rowbase + n0 + qB) * HD + colbase;
    bf16x8 qbA[4], qbB[4];
#pragma unroll
    for (int s = 0; s < 4; ++s) {
        qbA[s] = *(const bf16x8*)(qga + s * 16 + half * 8);
        qbB[s] = *(const bf16x8*)(qgb + s * 16 + half * 8);
    }

    // staging: 256 thr per team -> 64 rows x 4 granule-pairs of K and V
    const int ttid = tid & 255;
    const int srow = ttid >> 2, cp = (ttid & 3) * 2;
    const int swc0 = ((cp ^ (srow & 7)) * 8), swc1 = (((cp + 1) ^ (srow & 7)) * 8);
    const u16* kgp = Kg + (rowbase + srow) * HD + colbase + cp * 8 +
                     (size_t)cbase * 64 * HD;
    const u16* vgp = Vtg + ((size_t)bh * DH + srow) * NSEQ + cp * 8 + cbase * 64;
    // mask rows (cols cpos-permuted): lane's own two q rows, team's chunks
    const u16* mrowA = Madd2 + (size_t)(n0 + qA) * NSEQ + half * 16 + cbase * 64;
    const u16* mrowB = Madd2 + (size_t)(n0 + qB) * NSEQ + half * 16 + cbase * 64;

    // mask regs, team-chunk 0
    uint4 mA0a = *(const uint4*)(mrowA);
    uint4 mA0b = *(const uint4*)(mrowA + 8);
    uint4 mA1a = *(const uint4*)(mrowA + 32);
    uint4 mA1b = *(const uint4*)(mrowA + 40);
    uint4 mB0a = *(const uint4*)(mrowB);
    uint4 mB0b = *(const uint4*)(mrowB + 8);
    uint4 mB1a = *(const uint4*)(mrowB + 32);
    uint4 mB1b = *(const uint4*)(mrowB + 40);

    // K/V reg sets: s0 holds team-chunk 0 (staged immediately), s1 chunk 1
    uint4 s0k0, s0k1, s0v0, s0v1;
    uint4 s1k0, s1k1, s1v0, s1v1;
    s0k0 = *(const uint4*)kgp;       s0k1 = *(const uint4*)(kgp + 8);
    s0v0 = *(const uint4*)vgp;       s0v1 = *(const uint4*)(vgp + 8);
    *(uint4*)&Ks[team][0][srow * 64 + swc0] = s0k0;
    *(uint4*)&Ks[team][0][srow * 64 + swc1] = s0k1;
    *(uint4*)&Vs[team][0][srow * 64 + swc0] = s0v0;
    *(uint4*)&Vs[team][0][srow * 64 + swc1] = s0v1;
    s1k0 = *(const uint4*)(kgp + (size_t)64 * HD);
    s1k1 = *(const uint4*)(kgp + (size_t)64 * HD + 8);
    s1v0 = *(const uint4*)(vgp + 64);
    s1v1 = *(const uint4*)(vgp + 64 + 8);
    __syncthreads();

    float lA = 0.f, lB = 0.f;
    f32x16 OA0 = {}, OA1 = {}, OB0 = {}, OB1 = {};

#define CHUNK(CH, CUR, KW, KL)                                                 \
    {                                                                          \
        f32x16 sA0 = maskinit(mA0a, mA0b);                                     \
        f32x16 sA1 = maskinit(mA1a, mA1b);                                     \
        f32x16 sB0 = maskinit(mB0a, mB0b);                                     \
        f32x16 sB1 = maskinit(mB1a, mB1b);                                     \
        if ((CH) < 7) {                                                        \
            const u16* ma = mrowA + ((CH) + 1) * 64;                           \
            const u16* mb = mrowB + ((CH) + 1) * 64;                           \
            mA0a = *(const uint4*)(ma);      mA0b = *(const uint4*)(ma + 8);   \
            mA1a = *(const uint4*)(ma + 32); mA1b = *(const uint4*)(ma + 40);  \
            mB0a = *(const uint4*)(mb);      mB0b = *(const uint4*)(mb + 8);   \
            mB1a = *(const uint4*)(mb + 32); mB1b = *(const uint4*)(mb + 40);  \
        }                                                                      \
        _Pragma("unroll")                                                      \
        for (int s = 0; s < 4; ++s) {                                          \
            const int g = ((s * 2 + half) ^ q7) * 8;                           \
            bf16x8 ka0 = *(const bf16x8*)&Ks[team][CUR][l31 * 64 + g];         \
            bf16x8 ka1 = *(const bf16x8*)&Ks[team][CUR][(32 + l31) * 64 + g];  \
            sA0 = MFMA32(ka0, qbA[s], sA0);                                    \
            sA1 = MFMA32(ka1, qbA[s], sA1);                                    \
            sB0 = MFMA32(ka0, qbB[s], sB0);                                    \
            sB1 = MFMA32(ka1, qbB[s], sB1);                                    \
        }                                                                      \
        if ((CH) < 7) {                                                        \
            *(uint4*)&Ks[team][1 - (CUR)][srow * 64 + swc0] = KW##k0;          \
            *(uint4*)&Ks[team][1 - (CUR)][srow * 64 + swc1] = KW##k1;          \
            *(uint4*)&Vs[team][1 - (CUR)][srow * 64 + swc0] = KW##v0;          \
            *(uint4*)&Vs[team][1 - (CUR)][srow * 64 + swc1] = KW##v1;          \
        }                                                                      \
        if ((CH) < 6) {                                                        \
            const size_t ko = (size_t)((CH) + 2) * 64 * HD;                    \
            const int    vo = ((CH) + 2) * 64;                                 \
            KL##k0 = *(const uint4*)(kgp + ko);                                \
            KL##k1 = *(const uint4*)(kgp + ko + 8);                            \
            KL##v0 = *(const uint4*)(vgp + vo);                                \
            KL##v1 = *(const uint4*)(vgp + vo + 8);                            \
        }                                                                      \
        bf16x8 pbA[4], pbB[4];                                                 \
        lA += sm_pack(sA0, sA1, pbA);                                          \
        lB += sm_pack(sB0, sB1, pbB);                                          \
        _Pragma("unroll")                                                      \
        for (int s = 0; s < 4; ++s) {                                          \
            const int g = ((s * 2 + half) ^ q7) * 8;                           \
            bf16x8 va0 = *(const bf16x8*)&Vs[team][CUR][l31 * 64 + g];         \
            bf16x8 va1 = *(const bf16x8*)&Vs[team][CUR][(32 + l31) * 64 + g];  \
            OA0 = MFMA32(va0, pbA[s], OA0);                                    \
            OA1 = MFMA32(va1, pbA[s], OA1);                                    \
            OB0 = MFMA32(va0, pbB[s], OB0);                                    \
            OB1 = MFMA32(va1, pbB[s], OB1);                                    \
        }                                                                      \
        __syncthreads();                                                       \
    }

    for (int ch = 0; ch < 8; ch += 2) {
        CHUNK(ch,     0, s1, s0)
        CHUNK(ch + 1, 1, s0, s1)
    }
#undef CHUNK

    // ---- cross-team combine: no-max softmax => partials just add ----
    // Overlay the dead K/V buffers: Oex = 32 KB (one 8-group round),
    // Lex in Vs region. Two rounds: {OA0,OA1} then {OB0,OB1}.
    float4* Oex = (float4*)&Ks[0][0][0];   // 2048 float4 = 32 KB
    float*  Lex = (float*)&Vs[0][0][0];

    if (team == 1) {
#pragma unroll
        for (int g = 0; g < 4; ++g) {
            float4 t0, t1;
            t0.x = OA0[4 * g + 0]; t0.y = OA0[4 * g + 1];
            t0.z = OA0[4 * g + 2]; t0.w = OA0[4 * g + 3];
            t1.x = OA1[4 * g + 0]; t1.y = OA1[4 * g + 1];
            t1.z = OA1[4 * g + 2]; t1.w = OA1[4 * g + 3];
            Oex[(wq * 8 + g) * 64 + lane]     = t0;
            Oex[(wq * 8 + 4 + g) * 64 + lane] = t1;
        }
        Lex[wq * 128 + lane]      = lA;
        Lex[wq * 128 + 64 + lane] = lB;
    }
    __syncthreads();
    if (team == 0) {
        lA += Lex[wq * 128 + lane];
        lB += Lex[wq * 128 + 64 + lane];
#pragma unroll
        for (int g = 0; g < 4; ++g) {
            float4 t0 = Oex[(wq * 8 + g) * 64 + lane];
            float4 t1 = Oex[(wq * 8 + 4 + g) * 64 + lane];
            OA0[4 * g + 0] += t0.x; OA0[4 * g + 1] += t0.y;
            OA0[4 * g + 2] += t0.z; OA0[4 * g + 3] += t0.w;
            OA1[4 * g + 0] += t1.x; OA1[4 * g + 1] += t1.y;
            OA1[4 * g + 2] += t1.z; OA1[4 * g + 3] += t1.w;
        }
    }
    __syncthreads();
    if (team == 1) {
#pragma unroll
        for (int g = 0; g < 4; ++g) {
            float4 t0, t1;
            t0.x = OB0[4 * g + 0]; t0.y = OB0[4 * g + 1];
            t0.z = OB0[4 * g + 2]; t0.w = OB0[4 * g + 3];
            t1.x = OB1[4 * g + 0]; t1.y = OB1[4 * g + 1];
            t1.z = OB1[4 * g + 2]; t1.w = OB1[4 * g + 3];
            Oex[(wq * 8 + g) * 64 + lane]     = t0;
            Oex[(wq * 8 + 4 + g) * 64 + lane] = t1;
        }
    }
    __syncthreads();
    if (team == 0) {
#pragma unroll
        for (int g = 0; g < 4; ++g) {
            float4 t0 = Oex[(wq * 8 + g) * 64 + lane];
            float4 t1 = Oex[(wq * 8 + 4 + g) * 64 + lane];
            OB0[4 * g + 0] += t0.x; OB0[4 * g + 1] += t0.y;
            OB0[4 * g + 2] += t0.z; OB0[4 * g + 3] += t0.w;
            OB1[4 * g + 0] += t1.x; OB1[4 * g + 1] += t1.y;
            OB1[4 * g + 2] += t1.z; OB1[4 * g + 3] += t1.w;
        }

        // l: lanes l and l+32 hold disjoint key subsets of the same q
        lA += __shfl_xor(lA, 32, 64);
        lB += __shfl_xor(lB, 32, 64);
        const float invA = 1.0f / lA;
        const float invB = 1.0f / lB;

        float* orowA = out + (rowbase + n0 + qA) * HD + colbase;
        float* orowB = out + (rowbase + n0 + qB) * HD + colbase;
#pragma unroll
        for (int g = 0; g < 4; ++g) {
            const int d0 = 4 * half + 8 * g;
            float4 a0, a1, b0, b1;
            a0.x = OA0[4 * g + 0] * invA; a0.y = OA0[4 * g + 1] * invA;
            a0.z = OA0[4 * g + 2] * invA; a0.w = OA0[4 * g + 3] * invA;
            a1.x = OA1[4 * g + 0] * invA; a1.y = OA1[4 * g + 1] * invA;
            a1.z = OA1[4 * g + 2] * invA; a1.w = OA1[4 * g + 3] * invA;
            b0.x = OB0[4 * g + 0] * invB; b0.y = OB0[4 * g + 1] * invB;
            b0.z = OB0[4 * g + 2] * invB; b0.w = OB0[4 * g + 3] * invB;
            b1.x = OB1[4 * g + 0] * invB; b1.y = OB1[4 * g + 1] * invB;
            b1.z = OB1[4 * g + 2] * invB; b1.w = OB1[4 * g + 3] * invB;
            *(float4*)(orowA + d0)      = a0;
            *(float4*)(orowA + 32 + d0) = a1;
            *(float4*)(orowB + d0)      = b0;
            *(float4*)(orowB + 32 + d0) = b1;
        }
    }
}

// ============================================================
extern "C" void kernel_launch(void* const* d_in, const int* in_sizes, int n_in,
                              void* d_out, int out_size, void* d_ws, size_t ws_size,
                              hipStream_t stream) {
    const int*   adj = (const int*)d_in[0];
    const float* h   = (const float*)d_in[1];
    const float* Wq  = (const float*)d_in[2];
    const float* bq  = (const float*)d_in[3];
    const float* Wk  = (const float*)d_in[4];
    const float* bk  = (const float*)d_in[5];
    const float* Wv  = (const float*)d_in[6];
    const float* bv  = (const float*)d_in[7];
    float* outp = (float*)d_out;

    u16* Wt    = (u16*)d_ws;                                 // 3*512*256 u16
    u16* Qg    = Wt + (size_t)3 * HD * IN_DIM;               // 4 Mi u16 each
    u16* Kg    = Qg + (size_t)BATCH * NSEQ * HD;
    u16* Vtg   = Kg + (size_t)BATCH * NSEQ * HD;
    u16* Madd2 = Vtg + (size_t)BATCH * NSEQ * HD;            // 1 Mi u16
    (void)ws_size;

    wtrans_kernel<<<96, 256, 0, stream>>>(Wq, Wk, Wv, Wt);
    gemm_mask_kernel<<<dim3(BATCH * NSEQ / 64, 10), 256, 0, stream>>>(
        h, Wt, adj, bq, bk, bv, Qg, Kg, Vtg, Madd2);
    attn_kernel<<<dim3(BATCH * NHEADS, NSEQ / 256), 512, 0, stream>>>(
        Madd2, Qg, Kg, Vtg, outp);
}

// Round 4
// 150.994 us; speedup vs baseline: 1.2246x; 1.2218x over previous
//
#include <hip/hip_runtime.h>
#include <hip/hip_bf16.h>
#include <math.h>

#define IN_DIM 256
#define HD     512   // NUM_HEADS * OUT_DIM
#define NHEADS 8
#define DH     64
#define NSEQ   1024
#define BATCH  8

#define QSCALE 0.18033688011112042f   // 0.125 * log2(e): S in log2 domain

typedef unsigned short u16;
typedef unsigned int   u32;
typedef short bf16x8 __attribute__((ext_vector_type(8)));
typedef float f32x4  __attribute__((ext_vector_type(4)));
typedef float f32x16 __attribute__((ext_vector_type(16)));
typedef unsigned int u32x2 __attribute__((ext_vector_type(2)));

#if __has_builtin(__builtin_amdgcn_exp2f)
#define EXP2(x) __builtin_amdgcn_exp2f(x)
#else
#define EXP2(x) __expf(0.69314718056f * (x))
#endif

static __device__ __forceinline__ u16 f2bf(float x) {
    u32 u = __builtin_bit_cast(u32, x);
    u += 0x7FFFu + ((u >> 16) & 1u);     // RNE
    return (u16)(u >> 16);
}
static __device__ __forceinline__ u32 pk(u16 a, u16 b) {
    return (u32)a | ((u32)b << 16);
}
static __device__ __forceinline__ u32 cvtpk(float a, float b) {
    __hip_bfloat162 t = __float22bfloat162_rn(make_float2(a, b));
    u32 r; __builtin_memcpy(&r, &t, 4);
    return r;
}
// 16 bf16 (two uint4) -> f32x16 C-init
static __device__ __forceinline__ f32x16 maskinit(uint4 a, uint4 b) {
    f32x16 c;
    u32 ws[8] = {a.x, a.y, a.z, a.w, b.x, b.y, b.z, b.w};
#pragma unroll
    for (int i = 0; i < 8; ++i) {
        c[2 * i]     = __builtin_bit_cast(float, ws[i] << 16);
        c[2 * i + 1] = __builtin_bit_cast(float, ws[i] & 0xFFFF0000u);
    }
    return c;
}

// permlane32_swap: a' = [a_lo | b_lo], b' = [a_hi | b_hi] (32-lane rows)
static __device__ __forceinline__ void pswap(u32 &a, u32 &b) {
#if __has_builtin(__builtin_amdgcn_permlane32_swap)
    u32x2 r = __builtin_amdgcn_permlane32_swap(a, b, false, false);
    a = r.x; b = r.y;
#else
    const bool hi = (threadIdx.x & 32) != 0;
    u32 as = (u32)__shfl_xor((int)a, 32, 64);
    u32 bs = (u32)__shfl_xor((int)b, 32, 64);
    u32 na = hi ? bs : a;
    u32 nb = hi ? b  : as;
    a = na; b = nb;
#endif
}

#define MFMA32(a, b, c) __builtin_amdgcn_mfma_f32_32x32x16_bf16(a, b, c, 0, 0, 0)

// exp2 of ONE 32-key S^T tile, tree-sum, pack to bf16, permlane-exchange:
// pb[0], pb[1] are the B-frags for the two 16-key MFMA steps of this tile.
// Half-tile version keeps only one f32x16 S-tile live at a time (reg cap).
static __device__ __forceinline__ float sm_pack_half(const f32x16 st, bf16x8* pb) {
    float p[16];
#pragma unroll
    for (int r = 0; r < 16; ++r) p[r] = EXP2(st[r]);
    float t = (((p[0] + p[1]) + (p[2] + p[3])) + ((p[4] + p[5]) + (p[6] + p[7])))
            + (((p[8] + p[9]) + (p[10] + p[11])) + ((p[12] + p[13]) + (p[14] + p[15])));
    uint4 w0, w1;
    w0.x = cvtpk(p[0], p[1]);   w0.y = cvtpk(p[2], p[3]);
    w0.z = cvtpk(p[4], p[5]);   w0.w = cvtpk(p[6], p[7]);
    w1.x = cvtpk(p[8], p[9]);   w1.y = cvtpk(p[10], p[11]);
    w1.z = cvtpk(p[12], p[13]); w1.w = cvtpk(p[14], p[15]);
    pswap(w0.x, w1.x); pswap(w0.y, w1.y); pswap(w0.z, w1.z); pswap(w0.w, w1.w);
    pb[0] = __builtin_bit_cast(bf16x8, w0);
    pb[1] = __builtin_bit_cast(bf16x8, w1);
    return t;
}

// ============================================================
// W transpose: 96 blocks. W [K=256][N=512] fp32 -> Wt [N][K] bf16 (x3)
// ============================================================
__global__ __launch_bounds__(256)
void wtrans_kernel(const float* __restrict__ Wq, const float* __restrict__ Wk,
                   const float* __restrict__ Wv, u16* __restrict__ Wt)
{
    __shared__ float tile[64 * 65];
    const int bid = blockIdx.x, tid = threadIdx.x;
    const int k0 = (bid & 3) * 64, n0 = ((bid >> 2) & 7) * 64, wsel = bid >> 5;
    const float* W = (wsel == 0) ? Wq : (wsel == 1) ? Wk : Wv;
    u16* Out = Wt + (size_t)wsel * HD * IN_DIM;

    const int r = tid >> 2, c0 = (tid & 3) * 16;
#pragma unroll
    for (int j = 0; j < 16; j += 4) {
        float4 v = *(const float4*)(W + (size_t)(k0 + r) * HD + n0 + c0 + j);
        tile[r * 65 + c0 + j + 0] = v.x; tile[r * 65 + c0 + j + 1] = v.y;
        tile[r * 65 + c0 + j + 2] = v.z; tile[r * 65 + c0 + j + 3] = v.w;
    }
    __syncthreads();
    const int n = tid >> 2, ks = (tid & 3) * 16;
    u16 o[16];
#pragma unroll
    for (int j = 0; j < 16; ++j) o[j] = f2bf(tile[(ks + j) * 65 + n]);
    uint4 u0, u1;
    u0.x = pk(o[0], o[1]);   u0.y = pk(o[2], o[3]);
    u0.z = pk(o[4], o[5]);   u0.w = pk(o[6], o[7]);
    u1.x = pk(o[8], o[9]);   u1.y = pk(o[10], o[11]);
    u1.z = pk(o[12], o[13]); u1.w = pk(o[14], o[15]);
    u16* dst = Out + (size_t)(n0 + n) * IN_DIM + k0 + ks;
    *(uint4*)(dst) = u0;
    *(uint4*)(dst + 8) = u1;
}

// ============================================================
// Fused QKV GEMM + mask build, grid (128, 10):
//  y<8:  GEMM m-tile 64 x head y — 32x32x16 MFMA, acc 48 VGPR,
//        wave w owns (mh=w&1, nh=w>>1) 32x32 tile of Q,K,V.
//  y>=8: adj -> Madd2[q][64*ch + cpos(c)] bf16 {0,-3.39e38}
//        cpos(c) = 32*(c>>5) + 16*((c>>2)&1) + 4*((c>>3)&3) + (c&3)
// ============================================================
__global__ __launch_bounds__(256, 4)
void gemm_mask_kernel(const float* __restrict__ h, const u16* __restrict__ Wt,
                      const int* __restrict__ adj,
                      const float* __restrict__ bq, const float* __restrict__ bk,
                      const float* __restrict__ bv,
                      u16* __restrict__ Qg, u16* __restrict__ Kg,
                      u16* __restrict__ Vtg, u16* __restrict__ Madd2)
{
    __shared__ u16 pool[64 * 64 + 3 * 64 * 64];   // 32 KB
    const int tid = threadIdx.x;

    if (blockIdx.y >= 8) {
        // ---- adjacency -> bf16 additive mask, cpos-permuted cols ----
        int* tile = (int*)pool;              // [64][65] ints
        const int abid = (blockIdx.y - 8) * 128 + blockIdx.x;   // 0..255
        const int tR = abid >> 4, tC = abid & 15;   // q-tile, key-chunk
        const int r = tid >> 2, cg = (tid & 3) * 16;
        const int* src = adj + (size_t)(tR * 64 + r) * NSEQ + tC * 64 + cg;
#pragma unroll
        for (int j = 0; j < 16; j += 4) {
            int4 a = *(const int4*)(src + j);
            tile[r * 65 + cg + j + 0] = a.x; tile[r * 65 + cg + j + 1] = a.y;
            tile[r * 65 + cg + j + 2] = a.z; tile[r * 65 + cg + j + 3] = a.w;
        }
        __syncthreads();
        const int q = tid >> 2, p0 = (tid & 3) * 16;
        u16 o[16];
#pragma unroll
        for (int j = 0; j < 16; ++j) {
            const int p = p0 + j;
            const int c = 32 * (p >> 5) + (p & 3) + 4 * ((p >> 4) & 1) + 8 * ((p >> 2) & 3);
            o[j] = (tile[q * 65 + c] == 0) ? (u16)0xFF7F : (u16)0;
        }
        uint4 u0, u1;
        u0.x = pk(o[0], o[1]);   u0.y = pk(o[2], o[3]);
        u0.z = pk(o[4], o[5]);   u0.w = pk(o[6], o[7]);
        u1.x = pk(o[8], o[9]);   u1.y = pk(o[10], o[11]);
        u1.z = pk(o[12], o[13]); u1.w = pk(o[14], o[15]);
        u16* dst = Madd2 + (size_t)(tR * 64 + q) * NSEQ + tC * 64 + p0;
        *(uint4*)(dst) = u0;
        *(uint4*)(dst + 8) = u1;
        return;
    }

    // ---------------- GEMM branch (32x32x16) ----------------
    u16* As = pool;
    u16* Bs = pool + 64 * 64;

    const int m0 = blockIdx.x * 64;
    const int hh = blockIdx.y;
    const int n0 = hh * 64;

    const int w = tid >> 6, lane = tid & 63;
    const int l31 = lane & 31, half = lane >> 5;
    const int mh = w & 1, nh = w >> 1;
    const int s7 = l31 & 7;

    f32x16 acc[3] = {};   // Q, K, V 32x32 tiles

    const int arw = tid >> 2, acg = (tid & 3) * 2;
    const int brw = tid & 63, bgrp = tid >> 6;
    const float* srcA = h + (size_t)(m0 + arw) * IN_DIM;

    for (int kk = 0; kk < IN_DIM; kk += 64) {
        __syncthreads();
#pragma unroll
        for (int g = 0; g < 2; ++g) {
            const float* p = srcA + kk + (acg + g) * 8;
            float4 v0 = *(const float4*)(p);
            float4 v1 = *(const float4*)(p + 4);
            uint4 u;
            u.x = cvtpk(v0.x, v0.y); u.y = cvtpk(v0.z, v0.w);
            u.z = cvtpk(v1.x, v1.y); u.w = cvtpk(v1.z, v1.w);
            *(uint4*)&As[arw * 64 + (((acg + g) ^ (arw & 7)) * 8)] = u;
        }
#pragma unroll
        for (int i = 0; i < 6; ++i) {
            const int gc = bgrp * 6 + i;
            const int wh = gc >> 3, c8 = gc & 7;
            *(uint4*)&Bs[wh * 4096 + brw * 64 + ((c8 ^ (brw & 7)) * 8)] =
                *(const uint4*)(Wt + (size_t)wh * HD * IN_DIM +
                                (size_t)(n0 + brw) * IN_DIM + kk + c8 * 8);
        }
        __syncthreads();
        const int arow = (32 * mh + l31) * 64;
        const int brow = (32 * nh + l31) * 64;
#pragma unroll
        for (int s = 0; s < 4; ++s) {
            const int g = ((s * 2 + half) ^ s7) * 8;
            bf16x8 a = *(const bf16x8*)&As[arow + g];
#pragma unroll
            for (int wh = 0; wh < 3; ++wh) {
                bf16x8 b = *(const bf16x8*)&Bs[wh * 4096 + brow + g];
                acc[wh] = __builtin_amdgcn_mfma_f32_32x32x16_bf16(a, b, acc[wh], 0, 0, 0);
            }
        }
    }

    // ---- Q and K epilogues: LDS re-tile, coalesced stores ----
    // C-layout: col = 32*nh + l31, row = 32*mh + 4*half + (r&3) + 8*(r>>2)
    for (int which = 0; which < 2; ++which) {
        u16* T = pool;   // [64][72]
        const float* bias = (which == 0) ? bq : bk;
        u16* Out = (which == 0) ? Qg : Kg;
        const float scale = (which == 0) ? QSCALE : 1.0f;
        const float bvv = bias[n0 + 32 * nh + l31];
        __syncthreads();
#pragma unroll
        for (int r = 0; r < 16; ++r) {
            const int row = 32 * mh + 4 * half + (r & 3) + 8 * (r >> 2);
            T[row * 72 + 32 * nh + l31] = f2bf((acc[which][r] + bvv) * scale);
        }
        __syncthreads();
        const int row = tid >> 2, qc = (tid & 3) * 16;
        u16* dst = Out + (size_t)(m0 + row) * HD + n0 + qc;
        const u16* srcT = &T[row * 72 + qc];
        *(uint4*)(dst)     = *(const uint4*)(srcT);
        *(uint4*)(dst + 8) = *(const uint4*)(srcT + 8);
    }

    // ---- V epilogue: transpose + cpos permutation ----
    // m = 32*mh + 4*half + (r&3) + 8*(r>>2)  ->  pos(m) = 32*mh + 16*half + 4*(r>>2) + (r&3)
    {
        u16* T = pool;   // [64][72]  [d][pos]
        const int d = 32 * nh + l31;
        const float bvv = bv[n0 + d];
        __syncthreads();
#pragma unroll
        for (int g = 0; g < 4; ++g) {
            ushort4 o;
            o.x = f2bf(acc[2][4 * g + 0] + bvv);
            o.y = f2bf(acc[2][4 * g + 1] + bvv);
            o.z = f2bf(acc[2][4 * g + 2] + bvv);
            o.w = f2bf(acc[2][4 * g + 3] + bvv);
            *(ushort4*)&T[d * 72 + 32 * mh + 16 * half + 4 * g] = o;
        }
        __syncthreads();
        const int b = m0 >> 10, nloc = m0 & 1023;
        const int dd = tid >> 2, c = (tid & 3) * 16;
        u16* dst = Vtg + ((size_t)(b * NHEADS + hh) * DH + dd) * NSEQ + nloc + c;
        *(uint4*)(dst)     = *(uint4*)&T[dd * 72 + c];
        *(uint4*)(dst + 8) = *(uint4*)&T[dd * 72 + c + 8];
    }
}

// ============================================================
// Fused masked attention, 32x32x16 MFMA, no-max softmax.
// Round-4 structure:
//  - 256 thr (4 waves): teams by key-half (team = w>>1, chunks 0-7 / 8-15),
//    qrep=2 (wave owns 64 q), block covers 128 q. grid (64 bh, 8 qt) =
//    512 blocks = 2 blocks/CU = 2 waves/SIMD.
//  - Direct-global K/V A-frags (L1/L2-resident; same-bh blocks share an
//    XCD since flat wgid = qt*64+bh). No LDS staging, no in-loop barriers,
//    no prefetch registers.
//  - Half-chunk softmax: keys 0-31 fully processed (QK->exp->PV) before
//    keys 32-63, so only one pair of f32x16 S-tiles is live (reg cap).
//  - LDS = combine buffer padded to exactly 64 KB so the occupancy
//    heuristic targets 2 blocks/CU -> VGPR budget 256 (rounds 2/3: 64 KB
//    at 512 thr -> heuristic 4 waves/EU -> 128 VGPR -> 155 MB spill).
// ============================================================
__global__ __launch_bounds__(256, 2)
void attn_kernel(const u16* __restrict__ Madd2, const u16* __restrict__ Qg,
                 const u16* __restrict__ Kg, const u16* __restrict__ Vtg,
                 float* __restrict__ out)
{
    // only Oex[0..2048) + Lex used; tail is occupancy-heuristic padding
    __shared__ __align__(16) float4 Oex[2048 + 1984];   // 63 KB
    __shared__ float Lex[256];                           // 1 KB -> total 64 KB

    const int tid = threadIdx.x;
    const int w = tid >> 6, lane = tid & 63;
    const int team = w >> 1, wq = w & 1;
    const int l31 = lane & 31, half = lane >> 5;
    const int bh = blockIdx.x, qt = blockIdx.y;
    const int b = bh >> 3;
    const int n0 = qt * 128;
    const size_t rowbase = (size_t)b * NSEQ;
    const int colbase = (bh & 7) * DH;
    const int qA = wq * 64 + l31;         // block-local q row, tile A
    const int qB = qA + 32;               // tile B
    const int cbase = team * 8;           // team's first key chunk

    // Q B-frags (bf16, pre-scaled): B[k][q=l31]
    const u16* qga = Qg + (rowbase + n0 + qA) * HD + colbase;
    const u16* qgb = Qg + (rowbase + n0 + qB) * HD + colbase;
    bf16x8 qbA[4], qbB[4];
#pragma unroll
    for (int s = 0; s < 4; ++s) {
        qbA[s] = *(const bf16x8*)(qga + s * 16 + half * 8);
        qbB[s] = *(const bf16x8*)(qgb + s * 16 + half * 8);
    }

    // lane-resolved global bases
    // K A-frag: row = key (chunk-local l31 / 32+l31), granule (s*2+half) over d
    const u16* kb0 = Kg + (rowbase + cbase * 64 + l31) * HD + colbase + half * 8;
    const u16* kb1 = kb0 + 32 * HD;
    // V A-frag: row = d (l31 / 32+l31), granule (s*2+half) over cpos(keys)
    const u16* vb0 = Vtg + ((size_t)bh * DH + l31) * NSEQ + cbase * 64 + half * 8;
    const u16* vb1 = vb0 + 32 * NSEQ;
    // mask rows (cols cpos-permuted): lane's own two q rows, team's chunks
    const u16* mrowA = Madd2 + (size_t)(n0 + qA) * NSEQ + cbase * 64 + half * 16;
    const u16* mrowB = Madd2 + (size_t)(n0 + qB) * NSEQ + cbase * 64 + half * 16;

    // mask regs, team-chunk 0
    uint4 mA0a = *(const uint4*)(mrowA);
    uint4 mA0b = *(const uint4*)(mrowA + 8);
    uint4 mA1a = *(const uint4*)(mrowA + 32);
    uint4 mA1b = *(const uint4*)(mrowA + 40);
    uint4 mB0a = *(const uint4*)(mrowB);
    uint4 mB0b = *(const uint4*)(mrowB + 8);
    uint4 mB1a = *(const uint4*)(mrowB + 32);
    uint4 mB1b = *(const uint4*)(mrowB + 40);

    float lA = 0.f, lB = 0.f;
    f32x16 OA0 = {}, OA1 = {}, OB0 = {}, OB1 = {};

    for (int ch = 0; ch < 8; ++ch) {
        const u16* kr0 = kb0 + (size_t)ch * 64 * HD;
        const u16* kr1 = kb1 + (size_t)ch * 64 * HD;
        const u16* vr0 = vb0 + ch * 64;
        const u16* vr1 = vb1 + ch * 64;

        // ---- keys 0..31: QK ----
        f32x16 sA0 = maskinit(mA0a, mA0b);
        f32x16 sB0 = maskinit(mB0a, mB0b);
        {
            bf16x8 k0 = *(const bf16x8*)(kr0);
            bf16x8 k1 = *(const bf16x8*)(kr0 + 16);
            bf16x8 k2 = *(const bf16x8*)(kr0 + 32);
            bf16x8 k3 = *(const bf16x8*)(kr0 + 48);
            sA0 = MFMA32(k0, qbA[0], sA0); sB0 = MFMA32(k0, qbB[0], sB0);
            sA0 = MFMA32(k1, qbA[1], sA0); sB0 = MFMA32(k1, qbB[1], sB0);
            sA0 = MFMA32(k2, qbA[2], sA0); sB0 = MFMA32(k2, qbB[2], sB0);
            sA0 = MFMA32(k3, qbA[3], sA0); sB0 = MFMA32(k3, qbB[3], sB0);
        }
        bf16x8 pbA[2], pbB[2];
        lA += sm_pack_half(sA0, pbA);
        lB += sm_pack_half(sB0, pbB);

        // ---- keys 32..63: QK (S-tiles of half 0 now dead) ----
        f32x16 sA1 = maskinit(mA1a, mA1b);
        f32x16 sB1 = maskinit(mB1a, mB1b);
        if (ch < 7) {   // prefetch next chunk's masks (dist 1)
            const u16* ma = mrowA + (ch + 1) * 64;
            const u16* mb = mrowB + (ch + 1) * 64;
            mA0a = *(const uint4*)(ma);      mA0b = *(const uint4*)(ma + 8);
            mA1a = *(const uint4*)(ma + 32); mA1b = *(const uint4*)(ma + 40);
            mB0a = *(const uint4*)(mb);      mB0b = *(const uint4*)(mb + 8);
            mB1a = *(const uint4*)(mb + 32); mB1b = *(const uint4*)(mb + 40);
        }
        {
            bf16x8 k0 = *(const bf16x8*)(kr1);
            bf16x8 k1 = *(const bf16x8*)(kr1 + 16);
            bf16x8 k2 = *(const bf16x8*)(kr1 + 32);
            bf16x8 k3 = *(const bf16x8*)(kr1 + 48);
            sA1 = MFMA32(k0, qbA[0], sA1); sB1 = MFMA32(k0, qbB[0], sB1);
            sA1 = MFMA32(k1, qbA[1], sA1); sB1 = MFMA32(k1, qbB[1], sB1);
            sA1 = MFMA32(k2, qbA[2], sA1); sB1 = MFMA32(k2, qbB[2], sB1);
            sA1 = MFMA32(k3, qbA[3], sA1); sB1 = MFMA32(k3, qbB[3], sB1);
        }

        // ---- PV keys 0..31 (granules 0,1) ----
        {
            bf16x8 v00 = *(const bf16x8*)(vr0);
            bf16x8 v10 = *(const bf16x8*)(vr1);
            bf16x8 v01 = *(const bf16x8*)(vr0 + 16);
            bf16x8 v11 = *(const bf16x8*)(vr1 + 16);
            OA0 = MFMA32(v00, pbA[0], OA0); OA1 = MFMA32(v10, pbA[0], OA1);
            OB0 = MFMA32(v00, pbB[0], OB0); OB1 = MFMA32(v10, pbB[0], OB1);
            OA0 = MFMA32(v01, pbA[1], OA0); OA1 = MFMA32(v11, pbA[1], OA1);
            OB0 = MFMA32(v01, pbB[1], OB0); OB1 = MFMA32(v11, pbB[1], OB1);
        }

        // ---- softmax + PV keys 32..63 (granules 2,3) ----
        lA += sm_pack_half(sA1, pbA);
        lB += sm_pack_half(sB1, pbB);
        {
            bf16x8 v00 = *(const bf16x8*)(vr0 + 32);
            bf16x8 v10 = *(const bf16x8*)(vr1 + 32);
            bf16x8 v01 = *(const bf16x8*)(vr0 + 48);
            bf16x8 v11 = *(const bf16x8*)(vr1 + 48);
            OA0 = MFMA32(v00, pbA[0], OA0); OA1 = MFMA32(v10, pbA[0], OA1);
            OB0 = MFMA32(v00, pbB[0], OB0); OB1 = MFMA32(v10, pbB[0], OB1);
            OA0 = MFMA32(v01, pbA[1], OA0); OA1 = MFMA32(v11, pbA[1], OA1);
            OB0 = MFMA32(v01, pbB[1], OB0); OB1 = MFMA32(v11, pbB[1], OB1);
        }
    }

    // ---- cross-team combine: no-max softmax => partials just add ----
    // team1 parks all 16 float4/lane (OA0,OA1,OB0,OB1) + lA/lB in LDS;
    // team0 adds, normalizes, stores. One barrier total.
    if (team == 1) {
        const int base = wq * 16;
#pragma unroll
        for (int g = 0; g < 4; ++g) {
            float4 t;
            t.x = OA0[4 * g + 0]; t.y = OA0[4 * g + 1];
            t.z = OA0[4 * g + 2]; t.w = OA0[4 * g + 3];
            Oex[(base + g) * 64 + lane] = t;
            t.x = OA1[4 * g + 0]; t.y = OA1[4 * g + 1];
            t.z = OA1[4 * g + 2]; t.w = OA1[4 * g + 3];
            Oex[(base + 4 + g) * 64 + lane] = t;
            t.x = OB0[4 * g + 0]; t.y = OB0[4 * g + 1];
            t.z = OB0[4 * g + 2]; t.w = OB0[4 * g + 3];
            Oex[(base + 8 + g) * 64 + lane] = t;
            t.x = OB1[4 * g + 0]; t.y = OB1[4 * g + 1];
            t.z = OB1[4 * g + 2]; t.w = OB1[4 * g + 3];
            Oex[(base + 12 + g) * 64 + lane] = t;
        }
        Lex[(wq * 2 + 0) * 64 + lane] = lA;
        Lex[(wq * 2 + 1) * 64 + lane] = lB;
    }
    __syncthreads();
    if (team == 0) {
        const int base = wq * 16;
        lA += Lex[(wq * 2 + 0) * 64 + lane];
        lB += Lex[(wq * 2 + 1) * 64 + lane];
#pragma unroll
        for (int g = 0; g < 4; ++g) {
            float4 t0 = Oex[(base + g) * 64 + lane];
            float4 t1 = Oex[(base + 4 + g) * 64 + lane];
            float4 t2 = Oex[(base + 8 + g) * 64 + lane];
            float4 t3 = Oex[(base + 12 + g) * 64 + lane];
            OA0[4 * g + 0] += t0.x; OA0[4 * g + 1] += t0.y;
            OA0[4 * g + 2] += t0.z; OA0[4 * g + 3] += t0.w;
            OA1[4 * g + 0] += t1.x; OA1[4 * g + 1] += t1.y;
            OA1[4 * g + 2] += t1.z; OA1[4 * g + 3] += t1.w;
            OB0[4 * g + 0] += t2.x; OB0[4 * g + 1] += t2.y;
            OB0[4 * g + 2] += t2.z; OB0[4 * g + 3] += t2.w;
            OB1[4 * g + 0] += t3.x; OB1[4 * g + 1] += t3.y;
            OB1[4 * g + 2] += t3.z; OB1[4 * g + 3] += t3.w;
        }

        // l: lanes l and l+32 hold disjoint key subsets of the same q
        lA += __shfl_xor(lA, 32, 64);
        lB += __shfl_xor(lB, 32, 64);
        const float invA = 1.0f / lA;
        const float invB = 1.0f / lB;

        float* orowA = out + (rowbase + n0 + qA) * HD + colbase;
        float* orowB = out + (rowbase + n0 + qB) * HD + colbase;
#pragma unroll
        for (int g = 0; g < 4; ++g) {
            const int d0 = 4 * half + 8 * g;
            float4 a0, a1, b0, b1;
            a0.x = OA0[4 * g + 0] * invA; a0.y = OA0[4 * g + 1] * invA;
            a0.z = OA0[4 * g + 2] * invA; a0.w = OA0[4 * g + 3] * invA;
            a1.x = OA1[4 * g + 0] * invA; a1.y = OA1[4 * g + 1] * invA;
            a1.z = OA1[4 * g + 2] * invA; a1.w = OA1[4 * g + 3] * invA;
            b0.x = OB0[4 * g + 0] * invB; b0.y = OB0[4 * g + 1] * invB;
            b0.z = OB0[4 * g + 2] * invB; b0.w = OB0[4 * g + 3] * invB;
            b1.x = OB1[4 * g + 0] * invB; b1.y = OB1[4 * g + 1] * invB;
            b1.z = OB1[4 * g + 2] * invB; b1.w = OB1[4 * g + 3] * invB;
            *(float4*)(orowA + d0)      = a0;
            *(float4*)(orowA + 32 + d0) = a1;
            *(float4*)(orowB + d0)      = b0;
            *(float4*)(orowB + 32 + d0) = b1;
        }
    }
}

// ============================================================
extern "C" void kernel_launch(void* const* d_in, const int* in_sizes, int n_in,
                              void* d_out, int out_size, void* d_ws, size_t ws_size,
                              hipStream_t stream) {
    const int*   adj = (const int*)d_in[0];
    const float* h   = (const float*)d_in[1];
    const float* Wq  = (const float*)d_in[2];
    const float* bq  = (const float*)d_in[3];
    const float* Wk  = (const float*)d_in[4];
    const float* bk  = (const float*)d_in[5];
    const float* Wv  = (const float*)d_in[6];
    const float* bv  = (const float*)d_in[7];
    float* outp = (float*)d_out;

    u16* Wt    = (u16*)d_ws;                                 // 3*512*256 u16
    u16* Qg    = Wt + (size_t)3 * HD * IN_DIM;               // 4 Mi u16 each
    u16* Kg    = Qg + (size_t)BATCH * NSEQ * HD;
    u16* Vtg   = Kg + (size_t)BATCH * NSEQ * HD;
    u16* Madd2 = Vtg + (size_t)BATCH * NSEQ * HD;            // 1 Mi u16
    (void)ws_size;

    wtrans_kernel<<<96, 256, 0, stream>>>(Wq, Wk, Wv, Wt);
    gemm_mask_kernel<<<dim3(BATCH * NSEQ / 64, 10), 256, 0, stream>>>(
        h, Wt, adj, bq, bk, bv, Qg, Kg, Vtg, Madd2);
    attn_kernel<<<dim3(BATCH * NHEADS, NSEQ / 128), 256, 0, stream>>>(
        Madd2, Qg, Kg, Vtg, outp);
}

// Round 5
// 145.998 us; speedup vs baseline: 1.2665x; 1.0342x over previous
//
#include <hip/hip_runtime.h>
#include <hip/hip_bf16.h>
#include <math.h>

#define IN_DIM 256
#define HD     512   // NUM_HEADS * OUT_DIM
#define NHEADS 8
#define DH     64
#define NSEQ   1024
#define BATCH  8

#define QSCALE 0.18033688011112042f   // 0.125 * log2(e): S in log2 domain

typedef unsigned short u16;
typedef unsigned int   u32;
typedef short bf16x8 __attribute__((ext_vector_type(8)));
typedef float f32x4  __attribute__((ext_vector_type(4)));
typedef float f32x16 __attribute__((ext_vector_type(16)));
typedef unsigned int u32x2 __attribute__((ext_vector_type(2)));

#if __has_builtin(__builtin_amdgcn_exp2f)
#define EXP2(x) __builtin_amdgcn_exp2f(x)
#else
#define EXP2(x) __expf(0.69314718056f * (x))
#endif

static __device__ __forceinline__ u16 f2bf(float x) {
    u32 u = __builtin_bit_cast(u32, x);
    u += 0x7FFFu + ((u >> 16) & 1u);     // RNE
    return (u16)(u >> 16);
}
static __device__ __forceinline__ u32 pk(u16 a, u16 b) {
    return (u32)a | ((u32)b << 16);
}
static __device__ __forceinline__ u32 cvtpk(float a, float b) {
    __hip_bfloat162 t = __float22bfloat162_rn(make_float2(a, b));
    u32 r; __builtin_memcpy(&r, &t, 4);
    return r;
}
// 16 bf16 (two uint4) -> f32x16 C-init
static __device__ __forceinline__ f32x16 maskinit(uint4 a, uint4 b) {
    f32x16 c;
    u32 ws[8] = {a.x, a.y, a.z, a.w, b.x, b.y, b.z, b.w};
#pragma unroll
    for (int i = 0; i < 8; ++i) {
        c[2 * i]     = __builtin_bit_cast(float, ws[i] << 16);
        c[2 * i + 1] = __builtin_bit_cast(float, ws[i] & 0xFFFF0000u);
    }
    return c;
}

// permlane32_swap: a' = [a_lo | b_lo], b' = [a_hi | b_hi] (32-lane rows)
static __device__ __forceinline__ void pswap(u32 &a, u32 &b) {
#if __has_builtin(__builtin_amdgcn_permlane32_swap)
    u32x2 r = __builtin_amdgcn_permlane32_swap(a, b, false, false);
    a = r.x; b = r.y;
#else
    const bool hi = (threadIdx.x & 32) != 0;
    u32 as = (u32)__shfl_xor((int)a, 32, 64);
    u32 bs = (u32)__shfl_xor((int)b, 32, 64);
    u32 na = hi ? bs : a;
    u32 nb = hi ? b  : as;
    a = na; b = nb;
#endif
}

#define MFMA32(a, b, c) __builtin_amdgcn_mfma_f32_32x32x16_bf16(a, b, c, 0, 0, 0)

// exp2 of ONE 32-key S^T tile, tree-sum, pack to bf16, permlane-exchange:
// pb[0], pb[1] are the B-frags for the two 16-key MFMA steps of this tile.
// Half-tile version keeps only one f32x16 S-tile live at a time (reg cap).
static __device__ __forceinline__ float sm_pack_half(const f32x16 st, bf16x8* pb) {
    float p[16];
#pragma unroll
    for (int r = 0; r < 16; ++r) p[r] = EXP2(st[r]);
    float t = (((p[0] + p[1]) + (p[2] + p[3])) + ((p[4] + p[5]) + (p[6] + p[7])))
            + (((p[8] + p[9]) + (p[10] + p[11])) + ((p[12] + p[13]) + (p[14] + p[15])));
    uint4 w0, w1;
    w0.x = cvtpk(p[0], p[1]);   w0.y = cvtpk(p[2], p[3]);
    w0.z = cvtpk(p[4], p[5]);   w0.w = cvtpk(p[6], p[7]);
    w1.x = cvtpk(p[8], p[9]);   w1.y = cvtpk(p[10], p[11]);
    w1.z = cvtpk(p[12], p[13]); w1.w = cvtpk(p[14], p[15]);
    pswap(w0.x, w1.x); pswap(w0.y, w1.y); pswap(w0.z, w1.z); pswap(w0.w, w1.w);
    pb[0] = __builtin_bit_cast(bf16x8, w0);
    pb[1] = __builtin_bit_cast(bf16x8, w1);
    return t;
}

// ============================================================
// W transpose: 96 blocks. W [K=256][N=512] fp32 -> Wt [N][K] bf16 (x3)
// ============================================================
__global__ __launch_bounds__(256)
void wtrans_kernel(const float* __restrict__ Wq, const float* __restrict__ Wk,
                   const float* __restrict__ Wv, u16* __restrict__ Wt)
{
    __shared__ float tile[64 * 65];
    const int bid = blockIdx.x, tid = threadIdx.x;
    const int k0 = (bid & 3) * 64, n0 = ((bid >> 2) & 7) * 64, wsel = bid >> 5;
    const float* W = (wsel == 0) ? Wq : (wsel == 1) ? Wk : Wv;
    u16* Out = Wt + (size_t)wsel * HD * IN_DIM;

    const int r = tid >> 2, c0 = (tid & 3) * 16;
#pragma unroll
    for (int j = 0; j < 16; j += 4) {
        float4 v = *(const float4*)(W + (size_t)(k0 + r) * HD + n0 + c0 + j);
        tile[r * 65 + c0 + j + 0] = v.x; tile[r * 65 + c0 + j + 1] = v.y;
        tile[r * 65 + c0 + j + 2] = v.z; tile[r * 65 + c0 + j + 3] = v.w;
    }
    __syncthreads();
    const int n = tid >> 2, ks = (tid & 3) * 16;
    u16 o[16];
#pragma unroll
    for (int j = 0; j < 16; ++j) o[j] = f2bf(tile[(ks + j) * 65 + n]);
    uint4 u0, u1;
    u0.x = pk(o[0], o[1]);   u0.y = pk(o[2], o[3]);
    u0.z = pk(o[4], o[5]);   u0.w = pk(o[6], o[7]);
    u1.x = pk(o[8], o[9]);   u1.y = pk(o[10], o[11]);
    u1.z = pk(o[12], o[13]); u1.w = pk(o[14], o[15]);
    u16* dst = Out + (size_t)(n0 + n) * IN_DIM + k0 + ks;
    *(uint4*)(dst) = u0;
    *(uint4*)(dst + 8) = u1;
}

// ============================================================
// Fused QKV GEMM + mask build, grid (128, 10):
//  y<8:  GEMM m-tile 64 x head y — 32x32x16 MFMA, acc 48 VGPR,
//        wave w owns (mh=w&1, nh=w>>1) 32x32 tile of Q,K,V.
//  y>=8: adj -> Madd2[q][64*ch + cpos(c)] bf16 {0,-3.39e38}
//        cpos(c) = 32*(c>>5) + 16*((c>>2)&1) + 4*((c>>3)&3) + (c&3)
// ============================================================
__global__ __launch_bounds__(256, 4)
void gemm_mask_kernel(const float* __restrict__ h, const u16* __restrict__ Wt,
                      const int* __restrict__ adj,
                      const float* __restrict__ bq, const float* __restrict__ bk,
                      const float* __restrict__ bv,
                      u16* __restrict__ Qg, u16* __restrict__ Kg,
                      u16* __restrict__ Vtg, u16* __restrict__ Madd2)
{
    __shared__ u16 pool[64 * 64 + 3 * 64 * 64];   // 32 KB
    const int tid = threadIdx.x;

    if (blockIdx.y >= 8) {
        // ---- adjacency -> bf16 additive mask, cpos-permuted cols ----
        int* tile = (int*)pool;              // [64][65] ints
        const int abid = (blockIdx.y - 8) * 128 + blockIdx.x;   // 0..255
        const int tR = abid >> 4, tC = abid & 15;   // q-tile, key-chunk
        const int r = tid >> 2, cg = (tid & 3) * 16;
        const int* src = adj + (size_t)(tR * 64 + r) * NSEQ + tC * 64 + cg;
#pragma unroll
        for (int j = 0; j < 16; j += 4) {
            int4 a = *(const int4*)(src + j);
            tile[r * 65 + cg + j + 0] = a.x; tile[r * 65 + cg + j + 1] = a.y;
            tile[r * 65 + cg + j + 2] = a.z; tile[r * 65 + cg + j + 3] = a.w;
        }
        __syncthreads();
        const int q = tid >> 2, p0 = (tid & 3) * 16;
        u16 o[16];
#pragma unroll
        for (int j = 0; j < 16; ++j) {
            const int p = p0 + j;
            const int c = 32 * (p >> 5) + (p & 3) + 4 * ((p >> 4) & 1) + 8 * ((p >> 2) & 3);
            o[j] = (tile[q * 65 + c] == 0) ? (u16)0xFF7F : (u16)0;
        }
        uint4 u0, u1;
        u0.x = pk(o[0], o[1]);   u0.y = pk(o[2], o[3]);
        u0.z = pk(o[4], o[5]);   u0.w = pk(o[6], o[7]);
        u1.x = pk(o[8], o[9]);   u1.y = pk(o[10], o[11]);
        u1.z = pk(o[12], o[13]); u1.w = pk(o[14], o[15]);
        u16* dst = Madd2 + (size_t)(tR * 64 + q) * NSEQ + tC * 64 + p0;
        *(uint4*)(dst) = u0;
        *(uint4*)(dst + 8) = u1;
        return;
    }

    // ---------------- GEMM branch (32x32x16) ----------------
    u16* As = pool;
    u16* Bs = pool + 64 * 64;

    const int m0 = blockIdx.x * 64;
    const int hh = blockIdx.y;
    const int n0 = hh * 64;

    const int w = tid >> 6, lane = tid & 63;
    const int l31 = lane & 31, half = lane >> 5;
    const int mh = w & 1, nh = w >> 1;
    const int s7 = l31 & 7;

    f32x16 acc[3] = {};   // Q, K, V 32x32 tiles

    const int arw = tid >> 2, acg = (tid & 3) * 2;
    const int brw = tid & 63, bgrp = tid >> 6;
    const float* srcA = h + (size_t)(m0 + arw) * IN_DIM;

    for (int kk = 0; kk < IN_DIM; kk += 64) {
        __syncthreads();
#pragma unroll
        for (int g = 0; g < 2; ++g) {
            const float* p = srcA + kk + (acg + g) * 8;
            float4 v0 = *(const float4*)(p);
            float4 v1 = *(const float4*)(p + 4);
            uint4 u;
            u.x = cvtpk(v0.x, v0.y); u.y = cvtpk(v0.z, v0.w);
            u.z = cvtpk(v1.x, v1.y); u.w = cvtpk(v1.z, v1.w);
            *(uint4*)&As[arw * 64 + (((acg + g) ^ (arw & 7)) * 8)] = u;
        }
#pragma unroll
        for (int i = 0; i < 6; ++i) {
            const int gc = bgrp * 6 + i;
            const int wh = gc >> 3, c8 = gc & 7;
            *(uint4*)&Bs[wh * 4096 + brw * 64 + ((c8 ^ (brw & 7)) * 8)] =
                *(const uint4*)(Wt + (size_t)wh * HD * IN_DIM +
                                (size_t)(n0 + brw) * IN_DIM + kk + c8 * 8);
        }
        __syncthreads();
        const int arow = (32 * mh + l31) * 64;
        const int brow = (32 * nh + l31) * 64;
#pragma unroll
        for (int s = 0; s < 4; ++s) {
            const int g = ((s * 2 + half) ^ s7) * 8;
            bf16x8 a = *(const bf16x8*)&As[arow + g];
#pragma unroll
            for (int wh = 0; wh < 3; ++wh) {
                bf16x8 b = *(const bf16x8*)&Bs[wh * 4096 + brow + g];
                acc[wh] = __builtin_amdgcn_mfma_f32_32x32x16_bf16(a, b, acc[wh], 0, 0, 0);
            }
        }
    }

    // ---- Q and K epilogues: LDS re-tile, coalesced stores ----
    // C-layout: col = 32*nh + l31, row = 32*mh + 4*half + (r&3) + 8*(r>>2)
    for (int which = 0; which < 2; ++which) {
        u16* T = pool;   // [64][72]
        const float* bias = (which == 0) ? bq : bk;
        u16* Out = (which == 0) ? Qg : Kg;
        const float scale = (which == 0) ? QSCALE : 1.0f;
        const float bvv = bias[n0 + 32 * nh + l31];
        __syncthreads();
#pragma unroll
        for (int r = 0; r < 16; ++r) {
            const int row = 32 * mh + 4 * half + (r & 3) + 8 * (r >> 2);
            T[row * 72 + 32 * nh + l31] = f2bf((acc[which][r] + bvv) * scale);
        }
        __syncthreads();
        const int row = tid >> 2, qc = (tid & 3) * 16;
        u16* dst = Out + (size_t)(m0 + row) * HD + n0 + qc;
        const u16* srcT = &T[row * 72 + qc];
        *(uint4*)(dst)     = *(const uint4*)(srcT);
        *(uint4*)(dst + 8) = *(const uint4*)(srcT + 8);
    }

    // ---- V epilogue: transpose + cpos permutation ----
    // m = 32*mh + 4*half + (r&3) + 8*(r>>2)  ->  pos(m) = 32*mh + 16*half + 4*(r>>2) + (r&3)
    {
        u16* T = pool;   // [64][72]  [d][pos]
        const int d = 32 * nh + l31;
        const float bvv = bv[n0 + d];
        __syncthreads();
#pragma unroll
        for (int g = 0; g < 4; ++g) {
            ushort4 o;
            o.x = f2bf(acc[2][4 * g + 0] + bvv);
            o.y = f2bf(acc[2][4 * g + 1] + bvv);
            o.z = f2bf(acc[2][4 * g + 2] + bvv);
            o.w = f2bf(acc[2][4 * g + 3] + bvv);
            *(ushort4*)&T[d * 72 + 32 * mh + 16 * half + 4 * g] = o;
        }
        __syncthreads();
        const int b = m0 >> 10, nloc = m0 & 1023;
        const int dd = tid >> 2, c = (tid & 3) * 16;
        u16* dst = Vtg + ((size_t)(b * NHEADS + hh) * DH + dd) * NSEQ + nloc + c;
        *(uint4*)(dst)     = *(uint4*)&T[dd * 72 + c];
        *(uint4*)(dst + 8) = *(uint4*)&T[dd * 72 + c + 8];
    }
}

// ============================================================
// Fused masked attention, 32x32x16 MFMA, no-max softmax.
// Round-5 structure = round-1's LDS path + round-4's team/reg layout:
//  - 256 thr (4 waves): team = w>>1 over key halves (chunks 0-7 / 8-15),
//    wq = w&1 over q (qrep=2: wave owns 64 q). Block covers 128 q.
//    grid (64 bh, 8 qt) = 512 blocks = 2 blocks/CU = 2 waves/SIMD.
//  - K/V staged in LDS per team, double-buffered, XOR-swizzled granules
//    (coalesced global loads; round-4's direct-global row-gather was the
//    latency killer: 64 cache lines per A-frag load).
//  - Single staging reg set (32 VGPR): write chunk ch+1 to LDS, then
//    reload ch+2 -> one full chunk of latency cover.
//  - Half-chunk softmax: one f32x16 S-tile pair live at a time.
//  - LDS = 64 KB exactly (2 teams x 2 bufs x (K 8KB + V 8KB)) -> LDS
//    limit 2 blocks/CU, matching launch_bounds(256,2)'s 256-VGPR budget.
//  - Combine: team1 parks O/l in dead LDS, team0 adds+normalizes+stores.
// ============================================================
__global__ __launch_bounds__(256, 2)
void attn_kernel(const u16* __restrict__ Madd2, const u16* __restrict__ Qg,
                 const u16* __restrict__ Kg, const u16* __restrict__ Vtg,
                 float* __restrict__ out)
{
    __shared__ __align__(16) u16 Ks[4][4096];   // [team*2+buf][64 x 64]
    __shared__ __align__(16) u16 Vs[4][4096];   // [d][cpos(m)]

    const int tid = threadIdx.x;
    const int w = tid >> 6, lane = tid & 63;
    const int team = w >> 1, wq = w & 1;
    const int l31 = lane & 31, half = lane >> 5;
    const int bh = blockIdx.x, qt = blockIdx.y;
    const int b = bh >> 3;
    const int n0 = qt * 128;
    const size_t rowbase = (size_t)b * NSEQ;
    const int colbase = (bh & 7) * DH;
    const int q7 = l31 & 7;
    const int qA = wq * 64 + l31;         // block-local q row, tile A
    const int qB = qA + 32;               // tile B
    const int cbase = team * 8;           // team's first key chunk

    // Q B-frags (bf16, pre-scaled): B[k][q=l31]
    const u16* qga = Qg + (rowbase + n0 + qA) * HD + colbase;
    const u16* qgb = Qg + (rowbase + n0 + qB) * HD + colbase;
    bf16x8 qbA[4], qbB[4];
#pragma unroll
    for (int s = 0; s < 4; ++s) {
        qbA[s] = *(const bf16x8*)(qga + s * 16 + half * 8);
        qbB[s] = *(const bf16x8*)(qgb + s * 16 + half * 8);
    }

    // staging: 128 thr per team -> 64 rows x 8 granules of K and V
    // (each thread: 4 consecutive granules of one row, XOR-swizzled)
    const int ttid = tid & 127;
    const int srow = ttid >> 1, cg = (ttid & 1) * 4;
    const int sw0 = ((cg + 0) ^ (srow & 7)) * 8;
    const int sw1 = ((cg + 1) ^ (srow & 7)) * 8;
    const int sw2 = ((cg + 2) ^ (srow & 7)) * 8;
    const int sw3 = ((cg + 3) ^ (srow & 7)) * 8;
    const u16* kgp = Kg + (rowbase + cbase * 64 + srow) * HD + colbase + cg * 8;
    const u16* vgp = Vtg + ((size_t)bh * DH + srow) * NSEQ + cbase * 64 + cg * 8;
    // mask rows (cols cpos-permuted): lane's own two q rows, team's chunks
    const u16* mrowA = Madd2 + (size_t)(n0 + qA) * NSEQ + cbase * 64 + half * 16;
    const u16* mrowB = Madd2 + (size_t)(n0 + qB) * NSEQ + cbase * 64 + half * 16;

    // mask regs, team-chunk 0
    uint4 mA0a = *(const uint4*)(mrowA);
    uint4 mA0b = *(const uint4*)(mrowA + 8);
    uint4 mA1a = *(const uint4*)(mrowA + 32);
    uint4 mA1b = *(const uint4*)(mrowA + 40);
    uint4 mB0a = *(const uint4*)(mrowB);
    uint4 mB0b = *(const uint4*)(mrowB + 8);
    uint4 mB1a = *(const uint4*)(mrowB + 32);
    uint4 mB1b = *(const uint4*)(mrowB + 40);

    // prologue: chunk 0 -> LDS buf 0; chunk 1 -> regs (in flight)
    uint4 kq0, kq1, kq2, kq3, vq0, vq1, vq2, vq3;
    kq0 = *(const uint4*)(kgp);      kq1 = *(const uint4*)(kgp + 8);
    kq2 = *(const uint4*)(kgp + 16); kq3 = *(const uint4*)(kgp + 24);
    vq0 = *(const uint4*)(vgp);      vq1 = *(const uint4*)(vgp + 8);
    vq2 = *(const uint4*)(vgp + 16); vq3 = *(const uint4*)(vgp + 24);
    {
        u16* kd = &Ks[team * 2][srow * 64];
        u16* vd = &Vs[team * 2][srow * 64];
        *(uint4*)&kd[sw0] = kq0; *(uint4*)&kd[sw1] = kq1;
        *(uint4*)&kd[sw2] = kq2; *(uint4*)&kd[sw3] = kq3;
        *(uint4*)&vd[sw0] = vq0; *(uint4*)&vd[sw1] = vq1;
        *(uint4*)&vd[sw2] = vq2; *(uint4*)&vd[sw3] = vq3;
    }
    {
        const u16* kp = kgp + (size_t)64 * HD;
        const u16* vp = vgp + 64;
        kq0 = *(const uint4*)(kp);      kq1 = *(const uint4*)(kp + 8);
        kq2 = *(const uint4*)(kp + 16); kq3 = *(const uint4*)(kp + 24);
        vq0 = *(const uint4*)(vp);      vq1 = *(const uint4*)(vp + 8);
        vq2 = *(const uint4*)(vp + 16); vq3 = *(const uint4*)(vp + 24);
    }
    __syncthreads();

    float lA = 0.f, lB = 0.f;
    f32x16 OA0 = {}, OA1 = {}, OB0 = {}, OB1 = {};

    for (int ch = 0; ch < 8; ++ch) {
        const int cur = ch & 1;
        const u16* Kc = &Ks[team * 2 + cur][0];
        const u16* Vc = &Vs[team * 2 + cur][0];

        // ---- QK keys 0..31 ----
        f32x16 sA0 = maskinit(mA0a, mA0b);
        f32x16 sB0 = maskinit(mB0a, mB0b);
#pragma unroll
        for (int s = 0; s < 4; ++s) {
            const int g = ((s * 2 + half) ^ q7) * 8;
            bf16x8 ka = *(const bf16x8*)&Kc[l31 * 64 + g];
            sA0 = MFMA32(ka, qbA[s], sA0);
            sB0 = MFMA32(ka, qbB[s], sB0);
        }
        bf16x8 pbA[2], pbB[2];
        lA += sm_pack_half(sA0, pbA);
        lB += sm_pack_half(sB0, pbB);

        // ---- QK keys 32..63 (half-0 S-tiles now dead) ----
        f32x16 sA1 = maskinit(mA1a, mA1b);
        f32x16 sB1 = maskinit(mB1a, mB1b);
        if (ch < 7) {   // mask prefetch, dist 1
            const u16* ma = mrowA + (ch + 1) * 64;
            const u16* mb = mrowB + (ch + 1) * 64;
            mA0a = *(const uint4*)(ma);      mA0b = *(const uint4*)(ma + 8);
            mA1a = *(const uint4*)(ma + 32); mA1b = *(const uint4*)(ma + 40);
            mB0a = *(const uint4*)(mb);      mB0b = *(const uint4*)(mb + 8);
            mB1a = *(const uint4*)(mb + 32); mB1b = *(const uint4*)(mb + 40);
        }
#pragma unroll
        for (int s = 0; s < 4; ++s) {
            const int g = ((s * 2 + half) ^ q7) * 8;
            bf16x8 ka = *(const bf16x8*)&Kc[(32 + l31) * 64 + g];
            sA1 = MFMA32(ka, qbA[s], sA1);
            sB1 = MFMA32(ka, qbB[s], sB1);
        }

        // ---- stage chunk ch+1 regs -> LDS[1-cur]; reload ch+2 ----
        if (ch < 7) {
            u16* kd = &Ks[team * 2 + (1 - cur)][srow * 64];
            u16* vd = &Vs[team * 2 + (1 - cur)][srow * 64];
            *(uint4*)&kd[sw0] = kq0; *(uint4*)&kd[sw1] = kq1;
            *(uint4*)&kd[sw2] = kq2; *(uint4*)&kd[sw3] = kq3;
            *(uint4*)&vd[sw0] = vq0; *(uint4*)&vd[sw1] = vq1;
            *(uint4*)&vd[sw2] = vq2; *(uint4*)&vd[sw3] = vq3;
        }
        if (ch < 6) {
            const u16* kp = kgp + (size_t)(ch + 2) * 64 * HD;
            const u16* vp = vgp + (ch + 2) * 64;
            kq0 = *(const uint4*)(kp);      kq1 = *(const uint4*)(kp + 8);
            kq2 = *(const uint4*)(kp + 16); kq3 = *(const uint4*)(kp + 24);
            vq0 = *(const uint4*)(vp);      vq1 = *(const uint4*)(vp + 8);
            vq2 = *(const uint4*)(vp + 16); vq3 = *(const uint4*)(vp + 24);
        }

        // ---- PV keys 0..31 (sigma granules 0,1 per half) ----
#pragma unroll
        for (int s = 0; s < 2; ++s) {
            const int g = ((s * 2 + half) ^ q7) * 8;
            bf16x8 va0 = *(const bf16x8*)&Vc[l31 * 64 + g];
            bf16x8 va1 = *(const bf16x8*)&Vc[(32 + l31) * 64 + g];
            OA0 = MFMA32(va0, pbA[s], OA0); OA1 = MFMA32(va1, pbA[s], OA1);
            OB0 = MFMA32(va0, pbB[s], OB0); OB1 = MFMA32(va1, pbB[s], OB1);
        }

        // ---- softmax half 1 + PV keys 32..63 (granules 2,3) ----
        lA += sm_pack_half(sA1, pbA);
        lB += sm_pack_half(sB1, pbB);
#pragma unroll
        for (int s = 2; s < 4; ++s) {
            const int g = ((s * 2 + half) ^ q7) * 8;
            bf16x8 va0 = *(const bf16x8*)&Vc[l31 * 64 + g];
            bf16x8 va1 = *(const bf16x8*)&Vc[(32 + l31) * 64 + g];
            OA0 = MFMA32(va0, pbA[s - 2], OA0); OA1 = MFMA32(va1, pbA[s - 2], OA1);
            OB0 = MFMA32(va0, pbB[s - 2], OB0); OB1 = MFMA32(va1, pbB[s - 2], OB1);
        }
        __syncthreads();
    }

    // ---- cross-team combine: no-max softmax => partials just add ----
    // All compute done (final loop barrier). Overlay dead K/V LDS:
    // Oex = 32 KB over Ks, Lex over Vs.
    float4* Oex = (float4*)&Ks[0][0];   // 2048 float4 = 32 KB
    float*  Lex = (float*)&Vs[0][0];

    if (team == 1) {
        const int base = wq * 16;
#pragma unroll
        for (int g = 0; g < 4; ++g) {
            float4 t;
            t.x = OA0[4 * g + 0]; t.y = OA0[4 * g + 1];
            t.z = OA0[4 * g + 2]; t.w = OA0[4 * g + 3];
            Oex[(base + g) * 64 + lane] = t;
            t.x = OA1[4 * g + 0]; t.y = OA1[4 * g + 1];
            t.z = OA1[4 * g + 2]; t.w = OA1[4 * g + 3];
            Oex[(base + 4 + g) * 64 + lane] = t;
            t.x = OB0[4 * g + 0]; t.y = OB0[4 * g + 1];
            t.z = OB0[4 * g + 2]; t.w = OB0[4 * g + 3];
            Oex[(base + 8 + g) * 64 + lane] = t;
            t.x = OB1[4 * g + 0]; t.y = OB1[4 * g + 1];
            t.z = OB1[4 * g + 2]; t.w = OB1[4 * g + 3];
            Oex[(base + 12 + g) * 64 + lane] = t;
        }
        Lex[(wq * 2 + 0) * 64 + lane] = lA;
        Lex[(wq * 2 + 1) * 64 + lane] = lB;
    }
    __syncthreads();
    if (team == 0) {
        const int base = wq * 16;
        lA += Lex[(wq * 2 + 0) * 64 + lane];
        lB += Lex[(wq * 2 + 1) * 64 + lane];
#pragma unroll
        for (int g = 0; g < 4; ++g) {
            float4 t0 = Oex[(base + g) * 64 + lane];
            float4 t1 = Oex[(base + 4 + g) * 64 + lane];
            float4 t2 = Oex[(base + 8 + g) * 64 + lane];
            float4 t3 = Oex[(base + 12 + g) * 64 + lane];
            OA0[4 * g + 0] += t0.x; OA0[4 * g + 1] += t0.y;
            OA0[4 * g + 2] += t0.z; OA0[4 * g + 3] += t0.w;
            OA1[4 * g + 0] += t1.x; OA1[4 * g + 1] += t1.y;
            OA1[4 * g + 2] += t1.z; OA1[4 * g + 3] += t1.w;
            OB0[4 * g + 0] += t2.x; OB0[4 * g + 1] += t2.y;
            OB0[4 * g + 2] += t2.z; OB0[4 * g + 3] += t2.w;
            OB1[4 * g + 0] += t3.x; OB1[4 * g + 1] += t3.y;
            OB1[4 * g + 2] += t3.z; OB1[4 * g + 3] += t3.w;
        }

        // l: lanes l and l+32 hold disjoint key subsets of the same q
        lA += __shfl_xor(lA, 32, 64);
        lB += __shfl_xor(lB, 32, 64);
        const float invA = 1.0f / lA;
        const float invB = 1.0f / lB;

        float* orowA = out + (rowbase + n0 + qA) * HD + colbase;
        float* orowB = out + (rowbase + n0 + qB) * HD + colbase;
#pragma unroll
        for (int g = 0; g < 4; ++g) {
            const int d0 = 4 * half + 8 * g;
            float4 a0, a1, b0, b1;
            a0.x = OA0[4 * g + 0] * invA; a0.y = OA0[4 * g + 1] * invA;
            a0.z = OA0[4 * g + 2] * invA; a0.w = OA0[4 * g + 3] * invA;
            a1.x = OA1[4 * g + 0] * invA; a1.y = OA1[4 * g + 1] * invA;
            a1.z = OA1[4 * g + 2] * invA; a1.w = OA1[4 * g + 3] * invA;
            b0.x = OB0[4 * g + 0] * invB; b0.y = OB0[4 * g + 1] * invB;
            b0.z = OB0[4 * g + 2] * invB; b0.w = OB0[4 * g + 3] * invB;
            b1.x = OB1[4 * g + 0] * invB; b1.y = OB1[4 * g + 1] * invB;
            b1.z = OB1[4 * g + 2] * invB; b1.w = OB1[4 * g + 3] * invB;
            *(float4*)(orowA + d0)      = a0;
            *(float4*)(orowA + 32 + d0) = a1;
            *(float4*)(orowB + d0)      = b0;
            *(float4*)(orowB + 32 + d0) = b1;
        }
    }
}

// ============================================================
extern "C" void kernel_launch(void* const* d_in, const int* in_sizes, int n_in,
                              void* d_out, int out_size, void* d_ws, size_t ws_size,
                              hipStream_t stream) {
    const int*   adj = (const int*)d_in[0];
    const float* h   = (const float*)d_in[1];
    const float* Wq  = (const float*)d_in[2];
    const float* bq  = (const float*)d_in[3];
    const float* Wk  = (const float*)d_in[4];
    const float* bk  = (const float*)d_in[5];
    const float* Wv  = (const float*)d_in[6];
    const float* bv  = (const float*)d_in[7];
    float* outp = (float*)d_out;

    u16* Wt    = (u16*)d_ws;                                 // 3*512*256 u16
    u16* Qg    = Wt + (size_t)3 * HD * IN_DIM;               // 4 Mi u16 each
    u16* Kg    = Qg + (size_t)BATCH * NSEQ * HD;
    u16* Vtg   = Kg + (size_t)BATCH * NSEQ * HD;
    u16* Madd2 = Vtg + (size_t)BATCH * NSEQ * HD;            // 1 Mi u16
    (void)ws_size;

    wtrans_kernel<<<96, 256, 0, stream>>>(Wq, Wk, Wv, Wt);
    gemm_mask_kernel<<<dim3(BATCH * NSEQ / 64, 10), 256, 0, stream>>>(
        h, Wt, adj, bq, bk, bv, Qg, Kg, Vtg, Madd2);
    attn_kernel<<<dim3(BATCH * NHEADS, NSEQ / 128), 256, 0, stream>>>(
        Madd2, Qg, Kg, Vtg, outp);
}

// Round 7
// 132.063 us; speedup vs baseline: 1.4002x; 1.1055x over previous
//
#include <hip/hip_runtime.h>
#include <hip/hip_bf16.h>
#include <math.h>

#define IN_DIM 256
#define HD     512   // NUM_HEADS * OUT_DIM
#define NHEADS 8
#define DH     64
#define NSEQ   1024
#define BATCH  8

#define QSCALE 0.18033688011112042f   // 0.125 * log2(e): S in log2 domain

typedef unsigned short u16;
typedef unsigned int   u32;
typedef short bf16x8 __attribute__((ext_vector_type(8)));
typedef float f32x4  __attribute__((ext_vector_type(4)));
typedef float f32x16 __attribute__((ext_vector_type(16)));
typedef unsigned int u32x2 __attribute__((ext_vector_type(2)));

#if __has_builtin(__builtin_amdgcn_exp2f)
#define EXP2(x) __builtin_amdgcn_exp2f(x)
#else
#define EXP2(x) __expf(0.69314718056f * (x))
#endif

static __device__ __forceinline__ u16 f2bf(float x) {
    u32 u = __builtin_bit_cast(u32, x);
    u += 0x7FFFu + ((u >> 16) & 1u);     // RNE
    return (u16)(u >> 16);
}
static __device__ __forceinline__ u32 pk(u16 a, u16 b) {
    return (u32)a | ((u32)b << 16);
}
static __device__ __forceinline__ u32 cvtpk(float a, float b) {
    __hip_bfloat162 t = __float22bfloat162_rn(make_float2(a, b));
    u32 r; __builtin_memcpy(&r, &t, 4);
    return r;
}
// 16 bf16 (two uint4) -> f32x16 C-init
static __device__ __forceinline__ f32x16 maskinit(uint4 a, uint4 b) {
    f32x16 c;
    u32 ws[8] = {a.x, a.y, a.z, a.w, b.x, b.y, b.z, b.w};
#pragma unroll
    for (int i = 0; i < 8; ++i) {
        c[2 * i]     = __builtin_bit_cast(float, ws[i] << 16);
        c[2 * i + 1] = __builtin_bit_cast(float, ws[i] & 0xFFFF0000u);
    }
    return c;
}

// permlane32_swap: a' = [a_lo | b_lo], b' = [a_hi | b_hi] (32-lane rows)
static __device__ __forceinline__ void pswap(u32 &a, u32 &b) {
#if __has_builtin(__builtin_amdgcn_permlane32_swap)
    u32x2 r = __builtin_amdgcn_permlane32_swap(a, b, false, false);
    a = r.x; b = r.y;
#else
    const bool hi = (threadIdx.x & 32) != 0;
    u32 as = (u32)__shfl_xor((int)a, 32, 64);
    u32 bs = (u32)__shfl_xor((int)b, 32, 64);
    u32 na = hi ? bs : a;
    u32 nb = hi ? b  : as;
    a = na; b = nb;
#endif
}

#define MFMA32(a, b, c) __builtin_amdgcn_mfma_f32_32x32x16_bf16(a, b, c, 0, 0, 0)

// async global->LDS, 16 B/lane; LDS dest is wave-uniform base + lane*16
#define GLOAD16(G, L)                                                          \
    __builtin_amdgcn_global_load_lds(                                          \
        (const __attribute__((address_space(1))) unsigned int*)(const void*)(G),\
        (__attribute__((address_space(3))) unsigned int*)(void*)(L), 16, 0, 0)

// exp2 of ONE 32-key S^T tile, tree-sum, pack to bf16, permlane-exchange:
// pb[0], pb[1] are the B-frags for the two 16-key MFMA steps of this tile.
static __device__ __forceinline__ float sm_pack_half(const f32x16 st, bf16x8* pb) {
    float p[16];
#pragma unroll
    for (int r = 0; r < 16; ++r) p[r] = EXP2(st[r]);
    float t = (((p[0] + p[1]) + (p[2] + p[3])) + ((p[4] + p[5]) + (p[6] + p[7])))
            + (((p[8] + p[9]) + (p[10] + p[11])) + ((p[12] + p[13]) + (p[14] + p[15])));
    uint4 w0, w1;
    w0.x = cvtpk(p[0], p[1]);   w0.y = cvtpk(p[2], p[3]);
    w0.z = cvtpk(p[4], p[5]);   w0.w = cvtpk(p[6], p[7]);
    w1.x = cvtpk(p[8], p[9]);   w1.y = cvtpk(p[10], p[11]);
    w1.z = cvtpk(p[12], p[13]); w1.w = cvtpk(p[14], p[15]);
    pswap(w0.x, w1.x); pswap(w0.y, w1.y); pswap(w0.z, w1.z); pswap(w0.w, w1.w);
    pb[0] = __builtin_bit_cast(bf16x8, w0);
    pb[1] = __builtin_bit_cast(bf16x8, w1);
    return t;
}

// ============================================================
// W transpose: 96 blocks. W [K=256][N=512] fp32 -> Wt [N][K] bf16 (x3)
// ============================================================
__global__ __launch_bounds__(256)
void wtrans_kernel(const float* __restrict__ Wq, const float* __restrict__ Wk,
                   const float* __restrict__ Wv, u16* __restrict__ Wt)
{
    __shared__ float tile[64 * 65];
    const int bid = blockIdx.x, tid = threadIdx.x;
    const int k0 = (bid & 3) * 64, n0 = ((bid >> 2) & 7) * 64, wsel = bid >> 5;
    const float* W = (wsel == 0) ? Wq : (wsel == 1) ? Wk : Wv;
    u16* Out = Wt + (size_t)wsel * HD * IN_DIM;

    const int r = tid >> 2, c0 = (tid & 3) * 16;
#pragma unroll
    for (int j = 0; j < 16; j += 4) {
        float4 v = *(const float4*)(W + (size_t)(k0 + r) * HD + n0 + c0 + j);
        tile[r * 65 + c0 + j + 0] = v.x; tile[r * 65 + c0 + j + 1] = v.y;
        tile[r * 65 + c0 + j + 2] = v.z; tile[r * 65 + c0 + j + 3] = v.w;
    }
    __syncthreads();
    const int n = tid >> 2, ks = (tid & 3) * 16;
    u16 o[16];
#pragma unroll
    for (int j = 0; j < 16; ++j) o[j] = f2bf(tile[(ks + j) * 65 + n]);
    uint4 u0, u1;
    u0.x = pk(o[0], o[1]);   u0.y = pk(o[2], o[3]);
    u0.z = pk(o[4], o[5]);   u0.w = pk(o[6], o[7]);
    u1.x = pk(o[8], o[9]);   u1.y = pk(o[10], o[11]);
    u1.z = pk(o[12], o[13]); u1.w = pk(o[14], o[15]);
    u16* dst = Out + (size_t)(n0 + n) * IN_DIM + k0 + ks;
    *(uint4*)(dst) = u0;
    *(uint4*)(dst + 8) = u1;
}

// ============================================================
// Fused QKV GEMM + mask build, grid (128, 10):
//  y<8:  GEMM m-tile 64 x head y — 32x32x16 MFMA, acc 48 VGPR,
//        wave w owns (mh=w&1, nh=w>>1) 32x32 tile of Q,K,V.
//  y>=8: adj -> Madd2[q][64*ch + cpos(c)] bf16 {0,-3.39e38}
//        cpos(c) = 32*(c>>5) + 16*((c>>2)&1) + 4*((c>>3)&3) + (c&3)
// ============================================================
__global__ __launch_bounds__(256, 4)
void gemm_mask_kernel(const float* __restrict__ h, const u16* __restrict__ Wt,
                      const int* __restrict__ adj,
                      const float* __restrict__ bq, const float* __restrict__ bk,
                      const float* __restrict__ bv,
                      u16* __restrict__ Qg, u16* __restrict__ Kg,
                      u16* __restrict__ Vtg, u16* __restrict__ Madd2)
{
    __shared__ u16 pool[64 * 64 + 3 * 64 * 64];   // 32 KB
    const int tid = threadIdx.x;

    if (blockIdx.y >= 8) {
        // ---- adjacency -> bf16 additive mask, cpos-permuted cols ----
        int* tile = (int*)pool;              // [64][65] ints
        const int abid = (blockIdx.y - 8) * 128 + blockIdx.x;   // 0..255
        const int tR = abid >> 4, tC = abid & 15;   // q-tile, key-chunk
        const int r = tid >> 2, cg = (tid & 3) * 16;
        const int* src = adj + (size_t)(tR * 64 + r) * NSEQ + tC * 64 + cg;
#pragma unroll
        for (int j = 0; j < 16; j += 4) {
            int4 a = *(const int4*)(src + j);
            tile[r * 65 + cg + j + 0] = a.x; tile[r * 65 + cg + j + 1] = a.y;
            tile[r * 65 + cg + j + 2] = a.z; tile[r * 65 + cg + j + 3] = a.w;
        }
        __syncthreads();
        const int q = tid >> 2, p0 = (tid & 3) * 16;
        u16 o[16];
#pragma unroll
        for (int j = 0; j < 16; ++j) {
            const int p = p0 + j;
            const int c = 32 * (p >> 5) + (p & 3) + 4 * ((p >> 4) & 1) + 8 * ((p >> 2) & 3);
            o[j] = (tile[q * 65 + c] == 0) ? (u16)0xFF7F : (u16)0;
        }
        uint4 u0, u1;
        u0.x = pk(o[0], o[1]);   u0.y = pk(o[2], o[3]);
        u0.z = pk(o[4], o[5]);   u0.w = pk(o[6], o[7]);
        u1.x = pk(o[8], o[9]);   u1.y = pk(o[10], o[11]);
        u1.z = pk(o[12], o[13]); u1.w = pk(o[14], o[15]);
        u16* dst = Madd2 + (size_t)(tR * 64 + q) * NSEQ + tC * 64 + p0;
        *(uint4*)(dst) = u0;
        *(uint4*)(dst + 8) = u1;
        return;
    }

    // ---------------- GEMM branch (32x32x16) ----------------
    u16* As = pool;
    u16* Bs = pool + 64 * 64;

    const int m0 = blockIdx.x * 64;
    const int hh = blockIdx.y;
    const int n0 = hh * 64;

    const int w = tid >> 6, lane = tid & 63;
    const int l31 = lane & 31, half = lane >> 5;
    const int mh = w & 1, nh = w >> 1;
    const int s7 = l31 & 7;

    f32x16 acc[3] = {};   // Q, K, V 32x32 tiles

    const int arw = tid >> 2, acg = (tid & 3) * 2;
    const int brw = tid & 63, bgrp = tid >> 6;
    const float* srcA = h + (size_t)(m0 + arw) * IN_DIM;

    for (int kk = 0; kk < IN_DIM; kk += 64) {
        __syncthreads();
#pragma unroll
        for (int g = 0; g < 2; ++g) {
            const float* p = srcA + kk + (acg + g) * 8;
            float4 v0 = *(const float4*)(p);
            float4 v1 = *(const float4*)(p + 4);
            uint4 u;
            u.x = cvtpk(v0.x, v0.y); u.y = cvtpk(v0.z, v0.w);
            u.z = cvtpk(v1.x, v1.y); u.w = cvtpk(v1.z, v1.w);
            *(uint4*)&As[arw * 64 + (((acg + g) ^ (arw & 7)) * 8)] = u;
        }
#pragma unroll
        for (int i = 0; i < 6; ++i) {
            const int gc = bgrp * 6 + i;
            const int wh = gc >> 3, c8 = gc & 7;
            *(uint4*)&Bs[wh * 4096 + brw * 64 + ((c8 ^ (brw & 7)) * 8)] =
                *(const uint4*)(Wt + (size_t)wh * HD * IN_DIM +
                                (size_t)(n0 + brw) * IN_DIM + kk + c8 * 8);
        }
        __syncthreads();
        const int arow = (32 * mh + l31) * 64;
        const int brow = (32 * nh + l31) * 64;
#pragma unroll
        for (int s = 0; s < 4; ++s) {
            const int g = ((s * 2 + half) ^ s7) * 8;
            bf16x8 a = *(const bf16x8*)&As[arow + g];
#pragma unroll
            for (int wh = 0; wh < 3; ++wh) {
                bf16x8 b = *(const bf16x8*)&Bs[wh * 4096 + brow + g];
                acc[wh] = __builtin_amdgcn_mfma_f32_32x32x16_bf16(a, b, acc[wh], 0, 0, 0);
            }
        }
    }

    // ---- Q and K epilogues: LDS re-tile, coalesced stores ----
    // C-layout: col = 32*nh + l31, row = 32*mh + 4*half + (r&3) + 8*(r>>2)
    for (int which = 0; which < 2; ++which) {
        u16* T = pool;   // [64][72]
        const float* bias = (which == 0) ? bq : bk;
        u16* Out = (which == 0) ? Qg : Kg;
        const float scale = (which == 0) ? QSCALE : 1.0f;
        const float bvv = bias[n0 + 32 * nh + l31];
        __syncthreads();
#pragma unroll
        for (int r = 0; r < 16; ++r) {
            const int row = 32 * mh + 4 * half + (r & 3) + 8 * (r >> 2);
            T[row * 72 + 32 * nh + l31] = f2bf((acc[which][r] + bvv) * scale);
        }
        __syncthreads();
        const int row = tid >> 2, qc = (tid & 3) * 16;
        u16* dst = Out + (size_t)(m0 + row) * HD + n0 + qc;
        const u16* srcT = &T[row * 72 + qc];
        *(uint4*)(dst)     = *(const uint4*)(srcT);
        *(uint4*)(dst + 8) = *(const uint4*)(srcT + 8);
    }

    // ---- V epilogue: transpose + cpos permutation ----
    // m = 32*mh + 4*half + (r&3) + 8*(r>>2)  ->  pos(m) = 32*mh + 16*half + 4*(r>>2) + (r&3)
    {
        u16* T = pool;   // [64][72]  [d][pos]
        const int d = 32 * nh + l31;
        const float bvv = bv[n0 + d];
        __syncthreads();
#pragma unroll
        for (int g = 0; g < 4; ++g) {
            ushort4 o;
            o.x = f2bf(acc[2][4 * g + 0] + bvv);
            o.y = f2bf(acc[2][4 * g + 1] + bvv);
            o.z = f2bf(acc[2][4 * g + 2] + bvv);
            o.w = f2bf(acc[2][4 * g + 3] + bvv);
            *(ushort4*)&T[d * 72 + 32 * mh + 16 * half + 4 * g] = o;
        }
        __syncthreads();
        const int b = m0 >> 10, nloc = m0 & 1023;
        const int dd = tid >> 2, c = (tid & 3) * 16;
        u16* dst = Vtg + ((size_t)(b * NHEADS + hh) * DH + dd) * NSEQ + nloc + c;
        *(uint4*)(dst)     = *(uint4*)&T[dd * 72 + c];
        *(uint4*)(dst + 8) = *(uint4*)&T[dd * 72 + c + 8];
    }
}

// ============================================================
// Fused masked attention, 32x32x16 MFMA, no-max softmax.
// Round-7 = round-6 resubmit (container infra failure, kernel re-audited:
// DMA/LDS bounds in range, swizzle algebra verified, no divergent barrier).
//  - 512 thr (8 waves): team = w>>2 over key halves, j = w&3 over q
//    (qrep=1: wave owns 32 q). Block covers 128 q. grid (64 bh, 8 qt)
//    = 512 blocks = 2 blocks/CU = 16 waves/CU = 4 waves/SIMD.
//  - K/V staged via global_load_lds (async DMA, ZERO staging VGPRs,
//    no ds_writes). Swizzle preserved by inverse-swizzling the per-lane
//    GLOBAL source address (linear LDS dest, rule-21 pattern): DMA base
//    rows are 0 mod 8, so lane l -> row l>>3, slot l&7, source granule
//    (l&7)^(l>>3); read back at slot g^(row&7) as before.
//  - Single mask reg set (16 VGPR): ch+1 masks loaded into the same regs
//    right after ch's C-inits consume them (WAR keeps order, dist-1/2).
//  - Half-chunk softmax: one f32x16 S-tile live.
//  - Reg ledger: qb 16 + O 32 + S/p ~20 + pb 8 + m 16 + addr ~12 ~= 110-125.
//  - launch_bounds(512,4) caps VGPR at 128 (the 4-waves/SIMD tier).
//    Spill tell: WRITE_SIZE >> 17 MB.
// ============================================================
__global__ __launch_bounds__(512, 4)
void attn_kernel(const u16* __restrict__ Madd2, const u16* __restrict__ Qg,
                 const u16* __restrict__ Kg, const u16* __restrict__ Vtg,
                 float* __restrict__ out)
{
    __shared__ __align__(16) u16 Ks[2][2][4096];   // [team][buf][64 x 64]
    __shared__ __align__(16) u16 Vs[2][2][4096];   // [d][cpos(m)]

    const int tid = threadIdx.x;
    const int w = tid >> 6, lane = tid & 63;
    const int team = w >> 2, j = w & 3;
    const int l31 = lane & 31, half = lane >> 5;
    const int bh = blockIdx.x, qt = blockIdx.y;
    const int b = bh >> 3;
    const int n0 = qt * 128;
    const size_t rowbase = (size_t)b * NSEQ;
    const int colbase = (bh & 7) * DH;
    const int q7 = l31 & 7;
    const int qA = j * 32 + l31;          // block-local q row (wave's tile)
    const int cbase = team * 8;           // team's first key chunk

    // Q B-frags (bf16, pre-scaled): B[k][q=l31]
    const u16* qga = Qg + (rowbase + n0 + qA) * HD + colbase;
    bf16x8 qb[4];
#pragma unroll
    for (int s = 0; s < 4; ++s)
        qb[s] = *(const bf16x8*)(qga + s * 16 + half * 8);

    // ---- async staging geometry ----
    // wave j stages K rows [j*16, j*16+16) and V d-rows same, via 2+2
    // 1KB DMAs. Per-lane source: row j*16 + i*8 + (l>>3), granule
    // (l&7)^(l>>3) (inverse swizzle; base rows are 0 mod 8).
    const int lrow = lane >> 3, lgran = (lane & 7) ^ lrow;
    const int br0 = j * 16, br1 = j * 16 + 8;
    const u16* kg0 = Kg + (rowbase + cbase * 64 + br0 + lrow) * HD + colbase + lgran * 8;
    const u16* kg1 = kg0 + (size_t)8 * HD;
    const u16* vg0 = Vtg + ((size_t)bh * DH + br0 + lrow) * NSEQ + cbase * 64 + lgran * 8;
    const u16* vg1 = vg0 + (size_t)8 * NSEQ;

#define STAGE(BUF, CH)                                                   \
    do {                                                                 \
        GLOAD16(kg0 + (size_t)(CH) * 64 * HD, &Ks[team][BUF][br0 * 64]); \
        GLOAD16(kg1 + (size_t)(CH) * 64 * HD, &Ks[team][BUF][br1 * 64]); \
        GLOAD16(vg0 + (CH) * 64,              &Vs[team][BUF][br0 * 64]); \
        GLOAD16(vg1 + (CH) * 64,              &Vs[team][BUF][br1 * 64]); \
    } while (0)

    // mask rows (cols cpos-permuted): lane's own q row, team's chunks
    const u16* mrow = Madd2 + (size_t)(n0 + qA) * NSEQ + cbase * 64 + half * 16;

    // prologue: stage chunk 0, load chunk-0 masks; barrier drains DMA
    STAGE(0, 0);
    uint4 m0a = *(const uint4*)(mrow);
    uint4 m0b = *(const uint4*)(mrow + 8);
    uint4 m1a = *(const uint4*)(mrow + 32);
    uint4 m1b = *(const uint4*)(mrow + 40);
    __syncthreads();

    float l = 0.f;
    f32x16 O0 = {}, O1 = {};

    for (int ch = 0; ch < 8; ++ch) {
        const int cur = ch & 1;
        const u16* Kc = &Ks[team][cur][0];
        const u16* Vc = &Vs[team][cur][0];

        // issue next chunk's DMA now: full chunk of latency cover, the
        // end-of-chunk barrier is the vmcnt drain.
        if (ch < 7) STAGE(1 - cur, ch + 1);

        // ---- QK keys 0..31 (C-init = mask) ----
        f32x16 s0 = maskinit(m0a, m0b);
#pragma unroll
        for (int s = 0; s < 4; ++s) {
            const int g = ((s * 2 + half) ^ q7) * 8;
            bf16x8 ka = *(const bf16x8*)&Kc[l31 * 64 + g];
            s0 = MFMA32(ka, qb[s], s0);
        }
        bf16x8 pb[2];
        l += sm_pack_half(s0, pb);

        // ---- PV keys 0..31 (sigma granules 0,1) ----
#pragma unroll
        for (int s = 0; s < 2; ++s) {
            const int g = ((s * 2 + half) ^ q7) * 8;
            bf16x8 va0 = *(const bf16x8*)&Vc[l31 * 64 + g];
            bf16x8 va1 = *(const bf16x8*)&Vc[(32 + l31) * 64 + g];
            O0 = MFMA32(va0, pb[s], O0);
            O1 = MFMA32(va1, pb[s], O1);
        }

        // ---- QK keys 32..63 ----
        f32x16 s1 = maskinit(m1a, m1b);
        if (ch < 7) {   // reload masks for ch+1 into the SAME regs (WAR)
            const u16* mn = mrow + (ch + 1) * 64;
            m0a = *(const uint4*)(mn);      m0b = *(const uint4*)(mn + 8);
            m1a = *(const uint4*)(mn + 32); m1b = *(const uint4*)(mn + 40);
        }
#pragma unroll
        for (int s = 0; s < 4; ++s) {
            const int g = ((s * 2 + half) ^ q7) * 8;
            bf16x8 ka = *(const bf16x8*)&Kc[(32 + l31) * 64 + g];
            s1 = MFMA32(ka, qb[s], s1);
        }
        l += sm_pack_half(s1, pb);

        // ---- PV keys 32..63 (sigma granules 2,3) ----
#pragma unroll
        for (int s = 2; s < 4; ++s) {
            const int g = ((s * 2 + half) ^ q7) * 8;
            bf16x8 va0 = *(const bf16x8*)&Vc[l31 * 64 + g];
            bf16x8 va1 = *(const bf16x8*)&Vc[(32 + l31) * 64 + g];
            O0 = MFMA32(va0, pb[s - 2], O0);
            O1 = MFMA32(va1, pb[s - 2], O1);
        }
        __syncthreads();
    }
#undef STAGE

    // ---- cross-team combine: no-max softmax => partials just add ----
    // Overlay dead K/V LDS: Oex (32 KB) on Ks, Lex on Vs.
    float4* Oex = (float4*)&Ks[0][0][0];   // 2048 float4 = 32 KB
    float*  Lex = (float*)&Vs[0][0][0];

    if (team == 1) {
#pragma unroll
        for (int g = 0; g < 4; ++g) {
            float4 t;
            t.x = O0[4 * g + 0]; t.y = O0[4 * g + 1];
            t.z = O0[4 * g + 2]; t.w = O0[4 * g + 3];
            Oex[(j * 8 + g) * 64 + lane] = t;
            t.x = O1[4 * g + 0]; t.y = O1[4 * g + 1];
            t.z = O1[4 * g + 2]; t.w = O1[4 * g + 3];
            Oex[(j * 8 + 4 + g) * 64 + lane] = t;
        }
        Lex[j * 64 + lane] = l;
    }
    __syncthreads();
    if (team == 0) {
        l += Lex[j * 64 + lane];
#pragma unroll
        for (int g = 0; g < 4; ++g) {
            float4 t0 = Oex[(j * 8 + g) * 64 + lane];
            float4 t1 = Oex[(j * 8 + 4 + g) * 64 + lane];
            O0[4 * g + 0] += t0.x; O0[4 * g + 1] += t0.y;
            O0[4 * g + 2] += t0.z; O0[4 * g + 3] += t0.w;
            O1[4 * g + 0] += t1.x; O1[4 * g + 1] += t1.y;
            O1[4 * g + 2] += t1.z; O1[4 * g + 3] += t1.w;
        }

        // lanes l and l+32 hold disjoint key subsets of the same q
        l += __shfl_xor(l, 32, 64);
        const float inv = 1.0f / l;

        float* orow = out + (rowbase + n0 + qA) * HD + colbase;
#pragma unroll
        for (int g = 0; g < 4; ++g) {
            const int d0 = 4 * half + 8 * g;
            float4 a0, a1;
            a0.x = O0[4 * g + 0] * inv; a0.y = O0[4 * g + 1] * inv;
            a0.z = O0[4 * g + 2] * inv; a0.w = O0[4 * g + 3] * inv;
            a1.x = O1[4 * g + 0] * inv; a1.y = O1[4 * g + 1] * inv;
            a1.z = O1[4 * g + 2] * inv; a1.w = O1[4 * g + 3] * inv;
            *(float4*)(orow + d0)      = a0;
            *(float4*)(orow + 32 + d0) = a1;
        }
    }
}

// ============================================================
extern "C" void kernel_launch(void* const* d_in, const int* in_sizes, int n_in,
                              void* d_out, int out_size, void* d_ws, size_t ws_size,
                              hipStream_t stream) {
    const int*   adj = (const int*)d_in[0];
    const float* h   = (const float*)d_in[1];
    const float* Wq  = (const float*)d_in[2];
    const float* bq  = (const float*)d_in[3];
    const float* Wk  = (const float*)d_in[4];
    const float* bk  = (const float*)d_in[5];
    const float* Wv  = (const float*)d_in[6];
    const float* bv  = (const float*)d_in[7];
    float* outp = (float*)d_out;

    u16* Wt    = (u16*)d_ws;                                 // 3*512*256 u16
    u16* Qg    = Wt + (size_t)3 * HD * IN_DIM;               // 4 Mi u16 each
    u16* Kg    = Qg + (size_t)BATCH * NSEQ * HD;
    u16* Vtg   = Kg + (size_t)BATCH * NSEQ * HD;
    u16* Madd2 = Vtg + (size_t)BATCH * NSEQ * HD;            // 1 Mi u16
    (void)ws_size;

    wtrans_kernel<<<96, 256, 0, stream>>>(Wq, Wk, Wv, Wt);
    gemm_mask_kernel<<<dim3(BATCH * NSEQ / 64, 10), 256, 0, stream>>>(
        h, Wt, adj, bq, bk, bv, Qg, Kg, Vtg, Madd2);
    attn_kernel<<<dim3(BATCH * NHEADS, NSEQ / 128), 512, 0, stream>>>(
        Madd2, Qg, Kg, Vtg, outp);
}

// Round 8
// 124.479 us; speedup vs baseline: 1.4855x; 1.0609x over previous
//
#include <hip/hip_runtime.h>
#include <hip/hip_bf16.h>
#include <math.h>

#define IN_DIM 256
#define HD     512   // NUM_HEADS * OUT_DIM
#define NHEADS 8
#define DH     64
#define NSEQ   1024
#define BATCH  8

#define QSCALE 0.18033688011112042f   // 0.125 * log2(e): S in log2 domain

typedef unsigned short u16;
typedef unsigned int   u32;
typedef short bf16x8 __attribute__((ext_vector_type(8)));
typedef float f32x4  __attribute__((ext_vector_type(4)));
typedef float f32x16 __attribute__((ext_vector_type(16)));
typedef unsigned int u32x2 __attribute__((ext_vector_type(2)));

#if __has_builtin(__builtin_amdgcn_exp2f)
#define EXP2(x) __builtin_amdgcn_exp2f(x)
#else
#define EXP2(x) __expf(0.69314718056f * (x))
#endif

static __device__ __forceinline__ u16 f2bf(float x) {
    u32 u = __builtin_bit_cast(u32, x);
    u += 0x7FFFu + ((u >> 16) & 1u);     // RNE
    return (u16)(u >> 16);
}
static __device__ __forceinline__ u32 pk(u16 a, u16 b) {
    return (u32)a | ((u32)b << 16);
}
static __device__ __forceinline__ u32 cvtpk(float a, float b) {
    __hip_bfloat162 t = __float22bfloat162_rn(make_float2(a, b));
    u32 r; __builtin_memcpy(&r, &t, 4);
    return r;
}
// 16 bf16 (two uint4) -> f32x16 C-init
static __device__ __forceinline__ f32x16 maskinit(uint4 a, uint4 b) {
    f32x16 c;
    u32 ws[8] = {a.x, a.y, a.z, a.w, b.x, b.y, b.z, b.w};
#pragma unroll
    for (int i = 0; i < 8; ++i) {
        c[2 * i]     = __builtin_bit_cast(float, ws[i] << 16);
        c[2 * i + 1] = __builtin_bit_cast(float, ws[i] & 0xFFFF0000u);
    }
    return c;
}

// permlane32_swap: a' = [a_lo | b_lo], b' = [a_hi | b_hi] (32-lane rows)
static __device__ __forceinline__ void pswap(u32 &a, u32 &b) {
#if __has_builtin(__builtin_amdgcn_permlane32_swap)
    u32x2 r = __builtin_amdgcn_permlane32_swap(a, b, false, false);
    a = r.x; b = r.y;
#else
    const bool hi = (threadIdx.x & 32) != 0;
    u32 as = (u32)__shfl_xor((int)a, 32, 64);
    u32 bs = (u32)__shfl_xor((int)b, 32, 64);
    u32 na = hi ? bs : a;
    u32 nb = hi ? b  : as;
    a = na; b = nb;
#endif
}

#define MFMA32(a, b, c) __builtin_amdgcn_mfma_f32_32x32x16_bf16(a, b, c, 0, 0, 0)

// async global->LDS, 16 B/lane; LDS dest is wave-uniform base + lane*16
#define GLOAD16(G, L)                                                          \
    __builtin_amdgcn_global_load_lds(                                          \
        (const __attribute__((address_space(1))) unsigned int*)(const void*)(G),\
        (__attribute__((address_space(3))) unsigned int*)(void*)(L), 16, 0, 0)

// exp2 of ONE 32-key S^T tile, tree-sum, pack to bf16, permlane-exchange:
// pb[0], pb[1] are the B-frags for the two 16-key MFMA steps of this tile.
static __device__ __forceinline__ float sm_pack_half(const f32x16 st, bf16x8* pb) {
    float p[16];
#pragma unroll
    for (int r = 0; r < 16; ++r) p[r] = EXP2(st[r]);
    float t = (((p[0] + p[1]) + (p[2] + p[3])) + ((p[4] + p[5]) + (p[6] + p[7])))
            + (((p[8] + p[9]) + (p[10] + p[11])) + ((p[12] + p[13]) + (p[14] + p[15])));
    uint4 w0, w1;
    w0.x = cvtpk(p[0], p[1]);   w0.y = cvtpk(p[2], p[3]);
    w0.z = cvtpk(p[4], p[5]);   w0.w = cvtpk(p[6], p[7]);
    w1.x = cvtpk(p[8], p[9]);   w1.y = cvtpk(p[10], p[11]);
    w1.z = cvtpk(p[12], p[13]); w1.w = cvtpk(p[14], p[15]);
    pswap(w0.x, w1.x); pswap(w0.y, w1.y); pswap(w0.z, w1.z); pswap(w0.w, w1.w);
    pb[0] = __builtin_bit_cast(bf16x8, w0);
    pb[1] = __builtin_bit_cast(bf16x8, w1);
    return t;
}

// ============================================================
// W transpose + h->bf16: 224 blocks.
//  bid<96:  W [K=256][N=512] fp32 -> Wt [N][K] bf16 (x3)
//  bid>=96: h fp32 -> hb bf16 (elementwise, coalesced; removes the 8x
//           redundant per-head fp32->bf16 conversion in the QKV GEMM)
// ============================================================
__global__ __launch_bounds__(256)
void wtrans_kernel(const float* __restrict__ Wq, const float* __restrict__ Wk,
                   const float* __restrict__ Wv, const float* __restrict__ h,
                   u16* __restrict__ Wt, u16* __restrict__ hb)
{
    __shared__ float tile[64 * 65];
    const int bid = blockIdx.x, tid = threadIdx.x;

    if (bid >= 96) {
        // ---- h -> hb: 128 blocks x 4096 float4 ----
        const int ab = bid - 96;
        const float4* hs = (const float4*)h;
        uint2* hd = (uint2*)hb;
        const int base = ab * 4096 + tid;
#pragma unroll
        for (int j = 0; j < 16; ++j) {
            float4 v = hs[base + j * 256];
            uint2 o;
            o.x = cvtpk(v.x, v.y);
            o.y = cvtpk(v.z, v.w);
            hd[base + j * 256] = o;
        }
        return;
    }

    const int k0 = (bid & 3) * 64, n0 = ((bid >> 2) & 7) * 64, wsel = bid >> 5;
    const float* W = (wsel == 0) ? Wq : (wsel == 1) ? Wk : Wv;
    u16* Out = Wt + (size_t)wsel * HD * IN_DIM;

    const int r = tid >> 2, c0 = (tid & 3) * 16;
#pragma unroll
    for (int j = 0; j < 16; j += 4) {
        float4 v = *(const float4*)(W + (size_t)(k0 + r) * HD + n0 + c0 + j);
        tile[r * 65 + c0 + j + 0] = v.x; tile[r * 65 + c0 + j + 1] = v.y;
        tile[r * 65 + c0 + j + 2] = v.z; tile[r * 65 + c0 + j + 3] = v.w;
    }
    __syncthreads();
    const int n = tid >> 2, ks = (tid & 3) * 16;
    u16 o[16];
#pragma unroll
    for (int j = 0; j < 16; ++j) o[j] = f2bf(tile[(ks + j) * 65 + n]);
    uint4 u0, u1;
    u0.x = pk(o[0], o[1]);   u0.y = pk(o[2], o[3]);
    u0.z = pk(o[4], o[5]);   u0.w = pk(o[6], o[7]);
    u1.x = pk(o[8], o[9]);   u1.y = pk(o[10], o[11]);
    u1.z = pk(o[12], o[13]); u1.w = pk(o[14], o[15]);
    u16* dst = Out + (size_t)(n0 + n) * IN_DIM + k0 + ks;
    *(uint4*)(dst) = u0;
    *(uint4*)(dst + 8) = u1;
}

// ============================================================
// Fused QKV GEMM + mask build, grid (128, 10):
//  y<8:  GEMM m-tile 64 x head y — 32x32x16 MFMA, acc 48 VGPR,
//        wave w owns (mh=w&1, nh=w>>1) 32x32 tile of Q,K,V.
//        Round-8: staging via global_load_lds DMA (inverse-swizzled
//        source, rule-21 / attn-R7 pattern: 8x128B segments per DMA vs
//        the old row-gather's 64 cache lines per load), bf16 A from hb
//        (no in-loop cvtpk), double-buffered 2x32KB LDS, ONE barrier
//        per K-step, K-loop fully unrolled (static buffer indices).
//  y>=8: adj -> Madd2[q][64*ch + cpos(c)] bf16 {0,-3.39e38}
//        cpos(c) = 32*(c>>5) + 16*((c>>2)&1) + 4*((c>>3)&3) + (c&3)
// ============================================================
__global__ __launch_bounds__(256, 2)
void gemm_mask_kernel(const u16* __restrict__ hb, const u16* __restrict__ Wt,
                      const int* __restrict__ adj,
                      const float* __restrict__ bq, const float* __restrict__ bk,
                      const float* __restrict__ bv,
                      u16* __restrict__ Qg, u16* __restrict__ Kg,
                      u16* __restrict__ Vtg, u16* __restrict__ Madd2)
{
    // [buf] As 64x64 @ buf*4096 | Bs 3x64x64 @ 8192 + buf*12288  (64 KB)
    __shared__ __align__(16) u16 lds[32768];
    const int tid = threadIdx.x;

    if (blockIdx.y >= 8) {
        // ---- adjacency -> bf16 additive mask, cpos-permuted cols ----
        int* tile = (int*)lds;               // [64][65] ints
        const int abid = (blockIdx.y - 8) * 128 + blockIdx.x;   // 0..255
        const int tR = abid >> 4, tC = abid & 15;   // q-tile, key-chunk
        const int r = tid >> 2, cg = (tid & 3) * 16;
        const int* src = adj + (size_t)(tR * 64 + r) * NSEQ + tC * 64 + cg;
#pragma unroll
        for (int j = 0; j < 16; j += 4) {
            int4 a = *(const int4*)(src + j);
            tile[r * 65 + cg + j + 0] = a.x; tile[r * 65 + cg + j + 1] = a.y;
            tile[r * 65 + cg + j + 2] = a.z; tile[r * 65 + cg + j + 3] = a.w;
        }
        __syncthreads();
        const int q = tid >> 2, p0 = (tid & 3) * 16;
        u16 o[16];
#pragma unroll
        for (int j = 0; j < 16; ++j) {
            const int p = p0 + j;
            const int c = 32 * (p >> 5) + (p & 3) + 4 * ((p >> 4) & 1) + 8 * ((p >> 2) & 3);
            o[j] = (tile[q * 65 + c] == 0) ? (u16)0xFF7F : (u16)0;
        }
        uint4 u0, u1;
        u0.x = pk(o[0], o[1]);   u0.y = pk(o[2], o[3]);
        u0.z = pk(o[4], o[5]);   u0.w = pk(o[6], o[7]);
        u1.x = pk(o[8], o[9]);   u1.y = pk(o[10], o[11]);
        u1.z = pk(o[12], o[13]); u1.w = pk(o[14], o[15]);
        u16* dst = Madd2 + (size_t)(tR * 64 + q) * NSEQ + tC * 64 + p0;
        *(uint4*)(dst) = u0;
        *(uint4*)(dst + 8) = u1;
        return;
    }

    // ---------------- GEMM branch (32x32x16) ----------------
    const int m0 = blockIdx.x * 64;
    const int hh = blockIdx.y;
    const int n0 = hh * 64;

    const int w = tid >> 6, lane = tid & 63;
    const int l31 = lane & 31, half = lane >> 5;
    const int mh = w & 1, nh = w >> 1;
    const int s7 = l31 & 7;

    // DMA lane geometry (attn-R7 verified): stripe base rows r0 = 0 mod 8;
    // lane l -> row r0+(l>>3), LDS slot l&7, global granule (l&7)^(l>>3).
    const int lrow = lane >> 3, lgran = (lane & 7) ^ lrow;
    const int r0 = w * 16;
    const u16* ag = hb + (size_t)(m0 + r0 + lrow) * IN_DIM + lgran * 8;
    const u16* bg = Wt + (size_t)(n0 + r0 + lrow) * IN_DIM + lgran * 8;

#define STAGE_G(BUF, KK)                                                        \
    do {                                                                        \
        u16* a0 = lds + (BUF) * 4096 + r0 * 64;                                 \
        u16* b0 = lds + 8192 + (BUF) * 12288 + r0 * 64;                         \
        GLOAD16(ag + (KK) * 64,                                    a0);         \
        GLOAD16(ag + (KK) * 64 + 8 * IN_DIM,                       a0 + 512);   \
        GLOAD16(bg + (KK) * 64,                                    b0);         \
        GLOAD16(bg + (KK) * 64 + 8 * IN_DIM,                       b0 + 512);   \
        GLOAD16(bg + (KK) * 64 + (size_t)HD * IN_DIM,              b0 + 4096);  \
        GLOAD16(bg + (KK) * 64 + (size_t)HD * IN_DIM + 8 * IN_DIM, b0 + 4608);  \
        GLOAD16(bg + (KK) * 64 + (size_t)2 * HD * IN_DIM,          b0 + 8192);  \
        GLOAD16(bg + (KK) * 64 + (size_t)2 * HD * IN_DIM + 8 * IN_DIM, b0 + 8704); \
    } while (0)

    f32x16 acc[3] = {};   // Q, K, V 32x32 tiles
    const int arow = (32 * mh + l31) * 64;
    const int brow = (32 * nh + l31) * 64;

    STAGE_G(0, 0);
#pragma unroll
    for (int kk = 0; kk < 4; ++kk) {
        const int cur = kk & 1;
        __syncthreads();   // drains DMA for buf[cur]; buf[1-cur] reads done
        if (kk < 3) STAGE_G(1 - cur, kk + 1);
        const u16* Ac = lds + cur * 4096;
        const u16* Bc = lds + 8192 + cur * 12288;
#pragma unroll
        for (int s = 0; s < 4; ++s) {
            const int g = ((s * 2 + half) ^ s7) * 8;
            bf16x8 a = *(const bf16x8*)&Ac[arow + g];
#pragma unroll
            for (int wh = 0; wh < 3; ++wh) {
                bf16x8 b = *(const bf16x8*)&Bc[wh * 4096 + brow + g];
                acc[wh] = __builtin_amdgcn_mfma_f32_32x32x16_bf16(a, b, acc[wh], 0, 0, 0);
            }
        }
    }
#undef STAGE_G

    // ---- Q and K epilogues: LDS re-tile, coalesced stores ----
    // C-layout: col = 32*nh + l31, row = 32*mh + 4*half + (r&3) + 8*(r>>2)
    for (int which = 0; which < 2; ++which) {
        u16* T = lds;   // [64][72]
        const float* bias = (which == 0) ? bq : bk;
        u16* Out = (which == 0) ? Qg : Kg;
        const float scale = (which == 0) ? QSCALE : 1.0f;
        const float bvv = bias[n0 + 32 * nh + l31];
        __syncthreads();
#pragma unroll
        for (int r = 0; r < 16; ++r) {
            const int row = 32 * mh + 4 * half + (r & 3) + 8 * (r >> 2);
            T[row * 72 + 32 * nh + l31] = f2bf((acc[which][r] + bvv) * scale);
        }
        __syncthreads();
        const int row = tid >> 2, qc = (tid & 3) * 16;
        u16* dst = Out + (size_t)(m0 + row) * HD + n0 + qc;
        const u16* srcT = &T[row * 72 + qc];
        *(uint4*)(dst)     = *(const uint4*)(srcT);
        *(uint4*)(dst + 8) = *(const uint4*)(srcT + 8);
    }

    // ---- V epilogue: transpose + cpos permutation ----
    // m = 32*mh + 4*half + (r&3) + 8*(r>>2)  ->  pos(m) = 32*mh + 16*half + 4*(r>>2) + (r&3)
    {
        u16* T = lds;   // [64][72]  [d][pos]
        const int d = 32 * nh + l31;
        const float bvv = bv[n0 + d];
        __syncthreads();
#pragma unroll
        for (int g = 0; g < 4; ++g) {
            ushort4 o;
            o.x = f2bf(acc[2][4 * g + 0] + bvv);
            o.y = f2bf(acc[2][4 * g + 1] + bvv);
            o.z = f2bf(acc[2][4 * g + 2] + bvv);
            o.w = f2bf(acc[2][4 * g + 3] + bvv);
            *(ushort4*)&T[d * 72 + 32 * mh + 16 * half + 4 * g] = o;
        }
        __syncthreads();
        const int b = m0 >> 10, nloc = m0 & 1023;
        const int dd = tid >> 2, c = (tid & 3) * 16;
        u16* dst = Vtg + ((size_t)(b * NHEADS + hh) * DH + dd) * NSEQ + nloc + c;
        *(uint4*)(dst)     = *(uint4*)&T[dd * 72 + c];
        *(uint4*)(dst + 8) = *(uint4*)&T[dd * 72 + c + 8];
    }
}

// ============================================================
// Fused masked attention, 32x32x16 MFMA, no-max softmax.
// (unchanged from round 7 — 36 us est., 4 waves/SIMD, DMA staging)
//  - 512 thr (8 waves): team = w>>2 over key halves, j = w&3 over q
//    (qrep=1: wave owns 32 q). Block covers 128 q. grid (64 bh, 8 qt)
//    = 512 blocks = 2 blocks/CU = 16 waves/CU = 4 waves/SIMD.
//  - K/V staged via global_load_lds (async DMA, zero staging VGPRs).
//  - Single mask reg set; half-chunk softmax; permlane P-exchange.
// ============================================================
__global__ __launch_bounds__(512, 4)
void attn_kernel(const u16* __restrict__ Madd2, const u16* __restrict__ Qg,
                 const u16* __restrict__ Kg, const u16* __restrict__ Vtg,
                 float* __restrict__ out)
{
    __shared__ __align__(16) u16 Ks[2][2][4096];   // [team][buf][64 x 64]
    __shared__ __align__(16) u16 Vs[2][2][4096];   // [d][cpos(m)]

    const int tid = threadIdx.x;
    const int w = tid >> 6, lane = tid & 63;
    const int team = w >> 2, j = w & 3;
    const int l31 = lane & 31, half = lane >> 5;
    const int bh = blockIdx.x, qt = blockIdx.y;
    const int b = bh >> 3;
    const int n0 = qt * 128;
    const size_t rowbase = (size_t)b * NSEQ;
    const int colbase = (bh & 7) * DH;
    const int q7 = l31 & 7;
    const int qA = j * 32 + l31;          // block-local q row (wave's tile)
    const int cbase = team * 8;           // team's first key chunk

    // Q B-frags (bf16, pre-scaled): B[k][q=l31]
    const u16* qga = Qg + (rowbase + n0 + qA) * HD + colbase;
    bf16x8 qb[4];
#pragma unroll
    for (int s = 0; s < 4; ++s)
        qb[s] = *(const bf16x8*)(qga + s * 16 + half * 8);

    // ---- async staging geometry ----
    const int lrow = lane >> 3, lgran = (lane & 7) ^ lrow;
    const int br0 = j * 16, br1 = j * 16 + 8;
    const u16* kg0 = Kg + (rowbase + cbase * 64 + br0 + lrow) * HD + colbase + lgran * 8;
    const u16* kg1 = kg0 + (size_t)8 * HD;
    const u16* vg0 = Vtg + ((size_t)bh * DH + br0 + lrow) * NSEQ + cbase * 64 + lgran * 8;
    const u16* vg1 = vg0 + (size_t)8 * NSEQ;

#define STAGE(BUF, CH)                                                   \
    do {                                                                 \
        GLOAD16(kg0 + (size_t)(CH) * 64 * HD, &Ks[team][BUF][br0 * 64]); \
        GLOAD16(kg1 + (size_t)(CH) * 64 * HD, &Ks[team][BUF][br1 * 64]); \
        GLOAD16(vg0 + (CH) * 64,              &Vs[team][BUF][br0 * 64]); \
        GLOAD16(vg1 + (CH) * 64,              &Vs[team][BUF][br1 * 64]); \
    } while (0)

    // mask rows (cols cpos-permuted): lane's own q row, team's chunks
    const u16* mrow = Madd2 + (size_t)(n0 + qA) * NSEQ + cbase * 64 + half * 16;

    // prologue: stage chunk 0, load chunk-0 masks; barrier drains DMA
    STAGE(0, 0);
    uint4 m0a = *(const uint4*)(mrow);
    uint4 m0b = *(const uint4*)(mrow + 8);
    uint4 m1a = *(const uint4*)(mrow + 32);
    uint4 m1b = *(const uint4*)(mrow + 40);
    __syncthreads();

    float l = 0.f;
    f32x16 O0 = {}, O1 = {};

    for (int ch = 0; ch < 8; ++ch) {
        const int cur = ch & 1;
        const u16* Kc = &Ks[team][cur][0];
        const u16* Vc = &Vs[team][cur][0];

        // issue next chunk's DMA now: full chunk of latency cover, the
        // end-of-chunk barrier is the vmcnt drain.
        if (ch < 7) STAGE(1 - cur, ch + 1);

        // ---- QK keys 0..31 (C-init = mask) ----
        f32x16 s0 = maskinit(m0a, m0b);
#pragma unroll
        for (int s = 0; s < 4; ++s) {
            const int g = ((s * 2 + half) ^ q7) * 8;
            bf16x8 ka = *(const bf16x8*)&Kc[l31 * 64 + g];
            s0 = MFMA32(ka, qb[s], s0);
        }
        bf16x8 pb[2];
        l += sm_pack_half(s0, pb);

        // ---- PV keys 0..31 (sigma granules 0,1) ----
#pragma unroll
        for (int s = 0; s < 2; ++s) {
            const int g = ((s * 2 + half) ^ q7) * 8;
            bf16x8 va0 = *(const bf16x8*)&Vc[l31 * 64 + g];
            bf16x8 va1 = *(const bf16x8*)&Vc[(32 + l31) * 64 + g];
            O0 = MFMA32(va0, pb[s], O0);
            O1 = MFMA32(va1, pb[s], O1);
        }

        // ---- QK keys 32..63 ----
        f32x16 s1 = maskinit(m1a, m1b);
        if (ch < 7) {   // reload masks for ch+1 into the SAME regs (WAR)
            const u16* mn = mrow + (ch + 1) * 64;
            m0a = *(const uint4*)(mn);      m0b = *(const uint4*)(mn + 8);
            m1a = *(const uint4*)(mn + 32); m1b = *(const uint4*)(mn + 40);
        }
#pragma unroll
        for (int s = 0; s < 4; ++s) {
            const int g = ((s * 2 + half) ^ q7) * 8;
            bf16x8 ka = *(const bf16x8*)&Kc[(32 + l31) * 64 + g];
            s1 = MFMA32(ka, qb[s], s1);
        }
        l += sm_pack_half(s1, pb);

        // ---- PV keys 32..63 (sigma granules 2,3) ----
#pragma unroll
        for (int s = 2; s < 4; ++s) {
            const int g = ((s * 2 + half) ^ q7) * 8;
            bf16x8 va0 = *(const bf16x8*)&Vc[l31 * 64 + g];
            bf16x8 va1 = *(const bf16x8*)&Vc[(32 + l31) * 64 + g];
            O0 = MFMA32(va0, pb[s - 2], O0);
            O1 = MFMA32(va1, pb[s - 2], O1);
        }
        __syncthreads();
    }
#undef STAGE

    // ---- cross-team combine: no-max softmax => partials just add ----
    float4* Oex = (float4*)&Ks[0][0][0];   // 2048 float4 = 32 KB
    float*  Lex = (float*)&Vs[0][0][0];

    if (team == 1) {
#pragma unroll
        for (int g = 0; g < 4; ++g) {
            float4 t;
            t.x = O0[4 * g + 0]; t.y = O0[4 * g + 1];
            t.z = O0[4 * g + 2]; t.w = O0[4 * g + 3];
            Oex[(j * 8 + g) * 64 + lane] = t;
            t.x = O1[4 * g + 0]; t.y = O1[4 * g + 1];
            t.z = O1[4 * g + 2]; t.w = O1[4 * g + 3];
            Oex[(j * 8 + 4 + g) * 64 + lane] = t;
        }
        Lex[j * 64 + lane] = l;
    }
    __syncthreads();
    if (team == 0) {
        l += Lex[j * 64 + lane];
#pragma unroll
        for (int g = 0; g < 4; ++g) {
            float4 t0 = Oex[(j * 8 + g) * 64 + lane];
            float4 t1 = Oex[(j * 8 + 4 + g) * 64 + lane];
            O0[4 * g + 0] += t0.x; O0[4 * g + 1] += t0.y;
            O0[4 * g + 2] += t0.z; O0[4 * g + 3] += t0.w;
            O1[4 * g + 0] += t1.x; O1[4 * g + 1] += t1.y;
            O1[4 * g + 2] += t1.z; O1[4 * g + 3] += t1.w;
        }

        // lanes l and l+32 hold disjoint key subsets of the same q
        l += __shfl_xor(l, 32, 64);
        const float inv = 1.0f / l;

        float* orow = out + (rowbase + n0 + qA) * HD + colbase;
#pragma unroll
        for (int g = 0; g < 4; ++g) {
            const int d0 = 4 * half + 8 * g;
            float4 a0, a1;
            a0.x = O0[4 * g + 0] * inv; a0.y = O0[4 * g + 1] * inv;
            a0.z = O0[4 * g + 2] * inv; a0.w = O0[4 * g + 3] * inv;
            a1.x = O1[4 * g + 0] * inv; a1.y = O1[4 * g + 1] * inv;
            a1.z = O1[4 * g + 2] * inv; a1.w = O1[4 * g + 3] * inv;
            *(float4*)(orow + d0)      = a0;
            *(float4*)(orow + 32 + d0) = a1;
        }
    }
}

// ============================================================
extern "C" void kernel_launch(void* const* d_in, const int* in_sizes, int n_in,
                              void* d_out, int out_size, void* d_ws, size_t ws_size,
                              hipStream_t stream) {
    const int*   adj = (const int*)d_in[0];
    const float* h   = (const float*)d_in[1];
    const float* Wq  = (const float*)d_in[2];
    const float* bq  = (const float*)d_in[3];
    const float* Wk  = (const float*)d_in[4];
    const float* bk  = (const float*)d_in[5];
    const float* Wv  = (const float*)d_in[6];
    const float* bv  = (const float*)d_in[7];
    float* outp = (float*)d_out;

    u16* Wt    = (u16*)d_ws;                                 // 3*512*256 u16
    u16* Qg    = Wt + (size_t)3 * HD * IN_DIM;               // 4 Mi u16 each
    u16* Kg    = Qg + (size_t)BATCH * NSEQ * HD;
    u16* Vtg   = Kg + (size_t)BATCH * NSEQ * HD;
    u16* Madd2 = Vtg + (size_t)BATCH * NSEQ * HD;            // 1 Mi u16
    u16* hb    = Madd2 + (size_t)NSEQ * NSEQ;                // 2 Mi u16 (4 MB)
    (void)ws_size;

    wtrans_kernel<<<224, 256, 0, stream>>>(Wq, Wk, Wv, h, Wt, hb);
    gemm_mask_kernel<<<dim3(BATCH * NSEQ / 64, 10), 256, 0, stream>>>(
        hb, Wt, adj, bq, bk, bv, Qg, Kg, Vtg, Madd2);
    attn_kernel<<<dim3(BATCH * NHEADS, NSEQ / 128), 512, 0, stream>>>(
        Madd2, Qg, Kg, Vtg, outp);
}